// Round 9
// baseline (477.234 us; speedup 1.0000x reference)
//
#include <hip/hip_runtime.h>
#include <cstdint>
#include <cstddef>

// ---------------------------------------------------------------------------
// GCN 2-layer encoder.  Pipeline per launch (11 dispatches):
//   1. bin_count: 782-bin histogram of dst>>7
//   2. bin_scan:  binStart/binCursor (fine) + superCursor (dst>>11, 49 bins)
//   3. super_fill: partition edges into super-bins (1 tile/block)
//   4. fine_fill:  scatter each super-segment into its 16 fine bins
//   5. bin_csr: FUSED per-bin count + dis + scan + CSR col scatter
//      (binbuf second read is L2-hot; count[] round-trip eliminated)
//   6. wsplit: W1/W2 -> transposed split-bf16 planes [2][64][K] (hi, lo)
//   7. gemm1_mfma -> h1 bf16: 64-node tiles (24 KB LDS ring -> ~4-5
//      blocks/CU vs 2 at 48 KB; r5-r8 lesson: per-CU MLP was the cap).
//      Weights issued before the DMA wait; ledger vmcnt(10)/(8).
//   8. agg1 -> out1 (bf16, relu)  [fabric-roofline ~2.8 TB/s, left as-is]
//   9. gemm2_mfma -> h2 bf16 (64-node tiles, A exact bf16, 2-term)
//  10. agg2 -> d_out (fp32)
// MFMA orientation: D[n][m] = Wt[n][k] * x[m][k]^T so each lane holds 4
// consecutive output cols of one node -> packs straight into uint2 bf16.
// ---------------------------------------------------------------------------

#define BIN_SHIFT 7
#define BIN_NODES 128
#define MAX_BINS 1024
#define SUP_SHIFT 11
#define FINE_PER_SUP 16
#define NSUP_MAX 64
#define SCAP 56  // per-super staging capacity per 2048-edge tile (mean 42)
#define SRC_BITS 17
#define SRC_MASK ((1 << SRC_BITS) - 1)

typedef unsigned short ushort_t;

typedef __attribute__((ext_vector_type(8))) short bf16x8;  // 8 bf16 (4 VGPRs)
typedef __attribute__((ext_vector_type(4))) float f32x4;   // MFMA accumulator

union FragB {
  uint4 u;
  bf16x8 b;
};

__device__ __forceinline__ float4 bfq2f4(uint2 p) {  // 4 packed bf16 -> fp32 (exact)
  float4 r;
  r.x = __uint_as_float(p.x << 16);
  r.y = __uint_as_float(p.x & 0xFFFF0000u);
  r.z = __uint_as_float(p.y << 16);
  r.w = __uint_as_float(p.y & 0xFFFF0000u);
  return r;
}
__device__ __forceinline__ unsigned f2bf(float f) {  // fp32 -> bf16 bits, RNE
  unsigned u = __float_as_uint(f);
  return (u + 0x7FFFu + ((u >> 16) & 1u)) >> 16;
}
__device__ __forceinline__ uint2 f42bfq(float4 f) {
  uint2 r;
  r.x = f2bf(f.x) | (f2bf(f.y) << 16);
  r.y = f2bf(f.z) | (f2bf(f.w) << 16);
  return r;
}

__global__ void zero_int(int* __restrict__ p, int n) {
  int i = blockIdx.x * blockDim.x + threadIdx.x;
  if (i < n) p[i] = 0;
}

// --- pass 1: fine histogram -------------------------------------------------
__global__ __launch_bounds__(256) void bin_count(const int* __restrict__ dst, int E, int nbins,
                                                 int* __restrict__ binCnt) {
  __shared__ int h[MAX_BINS];
  for (int i = threadIdx.x; i < nbins; i += 256) h[i] = 0;
  __syncthreads();
  int stride = gridDim.x * 256;
  for (int e = blockIdx.x * 256 + threadIdx.x; e < E; e += stride)
    atomicAdd(&h[dst[e] >> BIN_SHIFT], 1);
  __syncthreads();
  for (int i = threadIdx.x; i < nbins; i += 256)
    if (h[i]) atomicAdd(&binCnt[i], h[i]);
}

// --- pass 2: scan fine bins; derive super cursors ---------------------------
__global__ __launch_bounds__(256) void bin_scan(const int* __restrict__ binCnt, int nbins, int E,
                                                int* __restrict__ binStart,
                                                int* __restrict__ binCursor,
                                                int* __restrict__ supCursor) {
  __shared__ int s[256];
  int t = threadIdx.x;
  int c[4];
  int sum = 0;
#pragma unroll
  for (int i = 0; i < 4; i++) {
    int idx = t * 4 + i;
    c[i] = (idx < nbins) ? binCnt[idx] : 0;
    sum += c[i];
  }
  int v = sum;
  s[t] = v;
  __syncthreads();
  for (int d = 1; d < 256; d <<= 1) {
    int add = (t >= d) ? s[t - d] : 0;
    __syncthreads();
    s[t] += add;
    __syncthreads();
  }
  int run = s[t] - v;  // exclusive prefix
#pragma unroll
  for (int i = 0; i < 4; i++) {
    int idx = t * 4 + i;
    if (idx < nbins) {
      binStart[idx] = run;
      binCursor[idx] = run;
      if ((idx & (FINE_PER_SUP - 1)) == 0) supCursor[idx >> 4] = run;  // super segment start
      run += c[i];
    }
  }
  if (t == 0) binStart[nbins] = E;
}

// --- pass 3: partition into super-bins, one 2048-edge tile per block --------
__global__ __launch_bounds__(256) void super_fill(const int* __restrict__ src,
                                                  const int* __restrict__ dst, int E, int nsup,
                                                  int* __restrict__ supCursor,
                                                  unsigned* __restrict__ supbuf) {
  __shared__ unsigned stage[NSUP_MAX * SCAP];
  __shared__ int lcnt[NSUP_MAX], lbase[NSUP_MAX], lscan[NSUP_MAX + 1];
  const int tid = threadIdx.x;
  const int t0 = blockIdx.x * 2048;
  const int t1 = min(E, t0 + 2048);

  int dv[8], sv[8];
#pragma unroll
  for (int i = 0; i < 8; i++) {
    int e = t0 + i * 256 + tid;
    if (e < t1) {
      dv[i] = dst[e];
      sv[i] = src[e];
    }
  }
  if (tid < nsup) lcnt[tid] = 0;
  __syncthreads();
#pragma unroll
  for (int i = 0; i < 8; i++) {
    int e = t0 + i * 256 + tid;
    if (e < t1) {
      int d = dv[i];
      int sb = d >> SUP_SHIFT;
      unsigned v = ((unsigned)(d & ((1 << SUP_SHIFT) - 1)) << SRC_BITS) | (unsigned)sv[i];
      int idx = atomicAdd(&lcnt[sb], 1);
      if (idx < SCAP)
        stage[sb * SCAP + idx] = v;
      else {  // rare overflow: direct write
        int g = atomicAdd(&supCursor[sb], 1);
        supbuf[g] = v;
      }
    }
  }
  __syncthreads();
  if (tid < nsup) {
    int c = min(lcnt[tid], SCAP);
    lcnt[tid] = c;
    lbase[tid] = c ? atomicAdd(&supCursor[tid], c) : 0;
  }
  __syncthreads();
  if (tid < 64) {  // wave-0 inclusive scan over 64 bins
    int vv = (tid < nsup) ? lcnt[tid] : 0;
    int ss = vv;
#pragma unroll
    for (int d = 1; d < 64; d <<= 1) {
      int u = __shfl_up(ss, d);
      if (tid >= d) ss += u;
    }
    lscan[tid + 1] = ss;
    if (tid == 0) lscan[0] = 0;
  }
  __syncthreads();
  int total = lscan[nsup];
  for (int j = tid; j < total; j += 256) {
    int lo = 0, hi = nsup;  // binary search: lscan[lo] <= j < lscan[lo+1]
    while (hi - lo > 1) {
      int mid = (lo + hi) >> 1;
      if (lscan[mid] <= j)
        lo = mid;
      else
        hi = mid;
    }
    int off = j - lscan[lo];
    supbuf[lbase[lo] + off] = stage[lo * SCAP + off];
  }
}

// --- pass 4: scatter super-segment into its 16 fine bins (L2 window) --------
__global__ __launch_bounds__(256) void fine_fill(const unsigned* __restrict__ supbuf,
                                                 const int* __restrict__ binStart, int nbins,
                                                 int* __restrict__ binCursor,
                                                 unsigned* __restrict__ binbuf) {
  __shared__ int lcnt[FINE_PER_SUP], lbase[FINE_PER_SUP];
  int sb = blockIdx.x >> 3, p = blockIdx.x & 7;
  int seg0 = binStart[sb << 4];
  int seg1 = binStart[min((sb + 1) << 4, nbins)];
  int part = (seg1 - seg0 + 7) >> 3;
  int c0 = seg0 + p * part;
  int c1 = min(seg1, c0 + part);
  if (threadIdx.x < FINE_PER_SUP) lcnt[threadIdx.x] = 0;
  __syncthreads();
  for (int i = c0 + threadIdx.x; i < c1; i += 256) atomicAdd(&lcnt[supbuf[i] >> 24], 1);
  __syncthreads();
  if (threadIdx.x < FINE_PER_SUP) {
    int c = lcnt[threadIdx.x];
    lbase[threadIdx.x] = c ? atomicAdd(&binCursor[(sb << 4) + threadIdx.x], c) : 0;
    lcnt[threadIdx.x] = 0;
  }
  __syncthreads();
  for (int i = c0 + threadIdx.x; i < c1; i += 256) {
    unsigned v = supbuf[i];
    unsigned dls = v >> SRC_BITS;  // 11-bit dst-local-to-super
    int f = dls >> BIN_SHIFT;      // fine bin within super
    unsigned vf = ((dls & (BIN_NODES - 1)) << SRC_BITS) | (v & SRC_MASK);
    int idx = lbase[f] + atomicAdd(&lcnt[f], 1);
    binbuf[idx] = vf;
  }
}

// --- pass 5: FUSED per-bin count + dis + scan + CSR col scatter -------------
__global__ __launch_bounds__(256) void bin_csr(const unsigned* __restrict__ binbuf,
                                               const int* __restrict__ binStart, int N, int E,
                                               int* __restrict__ rowptr, int* __restrict__ col,
                                               float* __restrict__ dis) {
  __shared__ int cnt[BIN_NODES];
  __shared__ int cur[BIN_NODES];
  __shared__ int pref[BIN_NODES];
  int b = blockIdx.x, t = threadIdx.x;
  int nodeBase = b << BIN_SHIFT;
  if (t < BIN_NODES) cnt[t] = 0;
  __syncthreads();
  int s0 = binStart[b], s1 = binStart[b + 1];
  for (int i = s0 + t; i < s1; i += 256) atomicAdd(&cnt[binbuf[i] >> SRC_BITS], 1);
  __syncthreads();
  int c = 0;
  if (t < BIN_NODES) {
    int node = nodeBase + t;
    if (node < N) {
      c = cnt[t];
      dis[node] = rsqrtf((float)(c + 1));  // +1 self loop
    }
    pref[t] = c;
  }
  __syncthreads();
  for (int d = 1; d < BIN_NODES; d <<= 1) {  // inclusive scan over 128
    int add = (t < BIN_NODES && t >= d) ? pref[t - d] : 0;
    __syncthreads();
    if (t < BIN_NODES) pref[t] += add;
    __syncthreads();
  }
  if (t < BIN_NODES) {
    int node = nodeBase + t;
    if (node < N) {
      int ex = s0 + pref[t] - c;  // exclusive prefix + segment base
      rowptr[node] = ex;
      cur[t] = ex;
    }
  }
  if (b == 0 && t == 255) rowptr[N] = E;
  __syncthreads();
  for (int i = s0 + t; i < s1; i += 256) {  // second read: L2-hot segment
    unsigned v = binbuf[i];
    int slot = atomicAdd(&cur[v >> SRC_BITS], 1);
    col[slot] = v & SRC_MASK;
  }
}

// --- pass 6: split W1/W2 into transposed bf16 hi/lo planes ------------------
__global__ __launch_bounds__(256) void wsplit(const float* __restrict__ W1,
                                              const float* __restrict__ W2,
                                              ushort_t* __restrict__ wt1,
                                              ushort_t* __restrict__ wt2) {
  int i = blockIdx.x * 256 + threadIdx.x;
  const float* W;
  ushort_t* wt;
  int K, idx;
  if (i < 256 * 64) {
    W = W1; wt = wt1; K = 256; idx = i;
  } else if (i < 256 * 64 + 64 * 64) {
    W = W2; wt = wt2; K = 64; idx = i - 256 * 64;
  } else
    return;
  int n = idx & 63, k = idx >> 6;
  float f = W[k * 64 + n];  // W is [K][64] row-major
  unsigned u = __float_as_uint(f);
  unsigned hb = u & 0xFFFF0000u;
  float lo = f - __uint_as_float(hb);
  wt[(size_t)n * K + k] = (ushort_t)(u >> 16);
  wt[(size_t)64 * K + (size_t)n * K + k] = (ushort_t)(__float_as_uint(lo) >> 16);
}

// split 8 packed fp32 (as 2 uint4) into bf16 hi (truncate) + lo (trunc resid)
__device__ __forceinline__ void split8u(uint4 a, uint4 b, uint4& xh, uint4& xl) {
  unsigned ua[8] = {a.x, a.y, a.z, a.w, b.x, b.y, b.z, b.w};
  unsigned hw[4], lw[4];
#pragma unroll
  for (int p = 0; p < 4; p++) {
    unsigned u0 = ua[2 * p], u1 = ua[2 * p + 1];
    unsigned h0 = u0 & 0xFFFF0000u, h1 = u1 & 0xFFFF0000u;
    float l0 = __uint_as_float(u0) - __uint_as_float(h0);
    float l1 = __uint_as_float(u1) - __uint_as_float(h1);
    hw[p] = (u0 >> 16) | h1;
    lw[p] = (__float_as_uint(l0) >> 16) | (__float_as_uint(l1) & 0xFFFF0000u);
  }
  xh = make_uint4(hw[0], hw[1], hw[2], hw[3]);
  xl = make_uint4(lw[0], lw[1], lw[2], lw[3]);
}

// --- gemm1: Cbf16[M][64] = x[M][256] @ W1, 64-node tiles, LDS-DMA ring ------
// Wave owns 16 nodes; per 32-wide k-tile it DMAs its 16 rows (2 KB) into a
// 3-buffer LDS ring via global_load_lds (2 calls x 1 KB).  24 KB LDS/block
// -> ~4-5 resident blocks/CU (vs 2 at the old 48 KB/128-node tile): per-CU
// DMA MLP doubles.  Weights issued BEFORE the DMA wait (L2 latency overlaps).
// Ledger: entering iter j queue=[st(j):2, st(j+1):2 (j<7)]; +w:8 ->
// vmcnt(10) drains exactly st(j) (j=7: vmcnt(8)).  Compiler MFMA-wait =
// vmcnt(2) keeps st(j+2) in flight.  No __syncthreads.
__global__ __launch_bounds__(256, 4) void gemm1_mfma(const float* __restrict__ A,
                                                     const ushort_t* __restrict__ Wt,
                                                     uint2* __restrict__ Cb, int M) {
  constexpr int K = 256;
  __shared__ uint4 xtile[3][4][128];  // [ring buf][wave][slot] = 24 KB
  const int lane = threadIdx.x & 63;
  const int wv = threadIdx.x >> 6;
  const int l15 = lane & 15;
  const int lq = lane >> 4;
  const int m0 = blockIdx.x * 64 + wv * 16;

  const ushort_t* __restrict__ Wlo = Wt + (size_t)64 * K;

  f32x4 acc[4];
#pragma unroll
  for (int b = 0; b < 4; b++) acc[b] = (f32x4){0.f, 0.f, 0.f, 0.f};

  // stage tile kt into ring buffer buf (this wave's 16 rows, 2 KB, 2 DMA calls)
  auto stage_tile = [&](int kt, int buf) {
#pragma unroll
    for (int c = 0; c < 2; c++) {
      int s = c * 64 + lane;           // 0..127
      int r = s >> 3;                  // row 0..15 within wave block
      int c4 = (s & 7) ^ (r & 7);      // swizzled float4-column
      int nd = m0 + r;
      if (nd >= M) nd = M - 1;
      const float* gp = A + (size_t)nd * K + kt * 32 + c4 * 4;
      __builtin_amdgcn_global_load_lds(
          (const __attribute__((address_space(1))) void*)gp,
          (__attribute__((address_space(3))) void*)&xtile[buf][wv][c * 64], 16, 0, 0);
    }
  };

  // prologue: st(0), st(1)
  stage_tile(0, 0);
  stage_tile(1, 1);
  __builtin_amdgcn_sched_barrier(0);

#pragma unroll
  for (int j = 0; j < 8; j++) {
    // a. issue this iteration's weight loads FIRST (L2 latency overlaps wait)
    FragB w[8];
    {
      const int kb = j * 32 + lq * 8;
#pragma unroll
      for (int nt = 0; nt < 4; nt++) {
        w[nt].u = *(const uint4*)(Wt + (size_t)(nt * 16 + l15) * K + kb);
        w[4 + nt].u = *(const uint4*)(Wlo + (size_t)(nt * 16 + l15) * K + kb);
      }
    }
    __builtin_amdgcn_sched_barrier(0);
    // b. ensure tile j staged: queue=[st(j):2, st(j+1):2 (j<7), w:8]
    if (j < 7)
      asm volatile("s_waitcnt vmcnt(10)" ::: "memory");
    else
      asm volatile("s_waitcnt vmcnt(8)" ::: "memory");
    __builtin_amdgcn_sched_barrier(0);
    // c. ds_read tile j fragments (swizzled); row = l15
    uint4 xa[2];
#pragma unroll
    for (int hh = 0; hh < 2; hh++) {
      int c4 = (lq * 2 + hh) ^ (l15 & 7);
      xa[hh] = *(const uint4*)&xtile[j % 3][wv][l15 * 8 + c4];
    }
    __builtin_amdgcn_sched_barrier(0);
    // d. issue stage for tile j+2
    if (j + 2 < 8) stage_tile(j + 2, (j + 2) % 3);
    __builtin_amdgcn_sched_barrier(0);
    // e. split + MFMA (compiler weight-wait = vmcnt(2), keeps st(j+2) alive)
    FragB xh0, xl0;
    split8u(xa[0], xa[1], xh0.u, xl0.u);
#pragma unroll
    for (int nt = 0; nt < 4; nt++) {
      acc[nt] = __builtin_amdgcn_mfma_f32_16x16x32_bf16(w[nt].b, xh0.b, acc[nt], 0, 0, 0);
      acc[nt] = __builtin_amdgcn_mfma_f32_16x16x32_bf16(w[nt].b, xl0.b, acc[nt], 0, 0, 0);
    }
#pragma unroll
    for (int nt = 0; nt < 4; nt++) {
      acc[nt] = __builtin_amdgcn_mfma_f32_16x16x32_bf16(w[4 + nt].b, xh0.b, acc[nt], 0, 0, 0);
    }
  }

  {
    int node = m0 + l15;
    if (node < M) {
      uint2* cp = Cb + (size_t)node * 16 + lq;
#pragma unroll
      for (int nt = 0; nt < 4; nt++) {
        float4 o = make_float4(acc[nt][0], acc[nt][1], acc[nt][2], acc[nt][3]);
        cp[nt * 4] = f42bfq(o);  // cols nt*16 + lq*4 .. +3
      }
    }
  }
}

// --- gemm2: Cbf16[M][64] = out1[M][64] @ W2 (64-node tiles, A exact bf16) ---
__global__ __launch_bounds__(256, 4) void gemm2_mfma(const ushort_t* __restrict__ Av,
                                                     const ushort_t* __restrict__ Wt,
                                                     uint2* __restrict__ Cb, int M) {
  constexpr int K = 64;
  constexpr int NT = K / 32;  // 2
  const int lane = threadIdx.x & 63;
  const int wv = threadIdx.x >> 6;
  const int l15 = lane & 15;
  const int lq = lane >> 4;
  const int m0 = blockIdx.x * 64 + wv * 16;

  const ushort_t* __restrict__ Wlo = Wt + (size_t)64 * K;

  f32x4 acc[4];
#pragma unroll
  for (int b = 0; b < 4; b++) acc[b] = (f32x4){0.f, 0.f, 0.f, 0.f};

  int node = m0 + l15;
  int ncl = node < M ? node : (M - 1);

  FragB xa[NT], wh[NT][4], wl[NT][4];
#pragma unroll
  for (int t = 0; t < NT; t++)
    xa[t].u = *(const uint4*)(Av + (size_t)ncl * K + t * 32 + lq * 8);
#pragma unroll
  for (int t = 0; t < NT; t++)
#pragma unroll
    for (int nt = 0; nt < 4; nt++) {
      wh[t][nt].u = *(const uint4*)(Wt + (size_t)(nt * 16 + l15) * K + t * 32 + lq * 8);
      wl[t][nt].u = *(const uint4*)(Wlo + (size_t)(nt * 16 + l15) * K + t * 32 + lq * 8);
    }
#pragma unroll
  for (int t = 0; t < NT; t++)
#pragma unroll
    for (int nt = 0; nt < 4; nt++) {
      acc[nt] = __builtin_amdgcn_mfma_f32_16x16x32_bf16(wh[t][nt].b, xa[t].b, acc[nt], 0, 0, 0);
      acc[nt] = __builtin_amdgcn_mfma_f32_16x16x32_bf16(wl[t][nt].b, xa[t].b, acc[nt], 0, 0, 0);
    }

  if (node < M) {
    uint2* cp = Cb + (size_t)node * 16 + lq;
#pragma unroll
    for (int nt = 0; nt < 4; nt++) {
      float4 o = make_float4(acc[nt][0], acc[nt][1], acc[nt][2], acc[nt][3]);
      cp[nt * 4] = f42bfq(o);
    }
  }
}

// --- aggregation: wave per node, depth-4 rolling gather pipeline ------------
// Fabric-roofline-bound (~165 MB L2-miss @ ~2.8 TB/s); structure kept.
template <bool OUTBF>
__global__ __launch_bounds__(256) void agg_kernel(
    const uint2* __restrict__ h, const int* __restrict__ rowptr, const int* __restrict__ col,
    const float* __restrict__ dis, const float* __restrict__ bias, void* __restrict__ outv,
    int N, int relu) {
  int wid = (blockIdx.x * blockDim.x + threadIdx.x) >> 6;
  if (wid >= N) return;
  int lane = threadIdx.x & 63;
  int sub = lane & 15;
  int quarter = lane >> 4;

  int start = rowptr[wid], end = rowptr[wid + 1];
  float di = dis[wid];

  float4 a0 = make_float4(0.f, 0.f, 0.f, 0.f), a1 = a0, a2 = a0, a3 = a0;
  {  // self-loop: di*h_self (quarter 0 only); final *di makes it di^2
    float4 self = bfq2f4(h[(size_t)wid * 16 + sub]);
    if (quarter == 0) {
      a0.x = di * self.x;
      a0.y = di * self.y;
      a0.z = di * self.z;
      a0.w = di * self.w;
    }
  }

  for (int base = start; base < end; base += 64) {
    int e = base + lane;
    int sj = 0;
    float wj = 0.f;
    if (e < end) {
      sj = col[e];
      wj = dis[sj];  // L2-resident 400 KB table
    }
    int cnt = end - base;
    if (cnt > 64) cnt = 64;
    int rounds = (cnt + 3) >> 2;  // wave-uniform

    uint2 g0, g1, g2, g3;
    float w0, w1, w2, w3;
#define ISSUE(gi, G, W)                                              \
  do {                                                               \
    int _i = (4 * (gi) + quarter) & 63;                              \
    int _s = __shfl(sj, _i);                                         \
    float _w = __shfl(wj, _i);                                       \
    if ((gi) < rounds) {                                             \
      G = h[(size_t)_s * 16 + sub];                                  \
      W = _w;                                                        \
    } else {                                                         \
      G = make_uint2(0u, 0u);                                        \
      W = 0.f;                                                       \
    }                                                                \
  } while (0)

    ISSUE(0, g0, w0);
    ISSUE(1, g1, w1);
    ISSUE(2, g2, w2);
    ISSUE(3, g3, w3);
    int rounds4 = (rounds + 3) & ~3;
    for (int t0 = 0; t0 < rounds4; t0 += 4) {
      {
        float4 gf = bfq2f4(g0);
        a0.x += w0 * gf.x; a0.y += w0 * gf.y; a0.z += w0 * gf.z; a0.w += w0 * gf.w;
      }
      ISSUE(t0 + 4, g0, w0);
      {
        float4 gf = bfq2f4(g1);
        a1.x += w1 * gf.x; a1.y += w1 * gf.y; a1.z += w1 * gf.z; a1.w += w1 * gf.w;
      }
      ISSUE(t0 + 5, g1, w1);
      {
        float4 gf = bfq2f4(g2);
        a2.x += w2 * gf.x; a2.y += w2 * gf.y; a2.z += w2 * gf.z; a2.w += w2 * gf.w;
      }
      ISSUE(t0 + 6, g2, w2);
      {
        float4 gf = bfq2f4(g3);
        a3.x += w3 * gf.x; a3.y += w3 * gf.y; a3.z += w3 * gf.z; a3.w += w3 * gf.w;
      }
      ISSUE(t0 + 7, g3, w3);
    }
#undef ISSUE
  }

  float sx = (a0.x + a1.x) + (a2.x + a3.x);
  float sy = (a0.y + a1.y) + (a2.y + a3.y);
  float sz = (a0.z + a1.z) + (a2.z + a3.z);
  float sw = (a0.w + a1.w) + (a2.w + a3.w);
  sx += __shfl_down(sx, 32); sy += __shfl_down(sy, 32);
  sz += __shfl_down(sz, 32); sw += __shfl_down(sw, 32);
  sx += __shfl_down(sx, 16); sy += __shfl_down(sy, 16);
  sz += __shfl_down(sz, 16); sw += __shfl_down(sw, 16);
  if (quarter == 0) {
    float4 bv = ((const float4*)bias)[sub];
    float4 o = make_float4(di * sx + bv.x, di * sy + bv.y, di * sz + bv.z, di * sw + bv.w);
    if (relu) {
      o.x = fmaxf(o.x, 0.f);
      o.y = fmaxf(o.y, 0.f);
      o.z = fmaxf(o.z, 0.f);
      o.w = fmaxf(o.w, 0.f);
    }
    if (OUTBF)
      ((uint2*)outv)[(size_t)wid * 16 + sub] = f42bfq(o);
    else
      ((float4*)outv)[(size_t)wid * 16 + sub] = o;
  }
}

// ---------------------------------------------------------------------------
extern "C" void kernel_launch(void* const* d_in, const int* in_sizes, int n_in,
                              void* d_out, int out_size, void* d_ws, size_t ws_size,
                              hipStream_t stream) {
  const float* x = (const float*)d_in[0];
  const int* ei = (const int*)d_in[1];
  const float* W1 = (const float*)d_in[2];
  const float* b1 = (const float*)d_in[3];
  const float* W2 = (const float*)d_in[4];
  const float* b2 = (const float*)d_in[5];

  const int IN = 256;
  const int E = in_sizes[1] / 2;
  const int N = in_sizes[0] / IN;
  const int* src = ei;
  const int* dst = ei + E;
  const int nbins = (N + BIN_NODES - 1) >> BIN_SHIFT;
  const int nsup = (N + (1 << SUP_SHIFT) - 1) >> SUP_SHIFT;

  // workspace carve-up (256B aligned)
  char* ws = (char*)d_ws;
  size_t off = 0;
  auto alloc = [&](size_t bytes) -> void* {
    void* p = ws + off;
    off += (bytes + 255) & ~(size_t)255;
    return p;
  };
  int* rowptr = (int*)alloc((size_t)(N + 1) * 4);
  float* dis = (float*)alloc((size_t)N * 4);
  int* binCnt = (int*)alloc(MAX_BINS * 4);
  int* binStart = (int*)alloc((MAX_BINS + 1) * 4);
  int* binCursor = (int*)alloc(MAX_BINS * 4);
  int* supCursor = (int*)alloc(NSUP_MAX * 4);
  int* col = (int*)alloc((size_t)E * 4);                // 12.8 MB; written by bin_csr
  unsigned* supbuf = (unsigned*)col;                    // alias: dead before col written
  uint2* out1 = (uint2*)alloc((size_t)N * 64 * 2);      // bf16 layer-1 activations
  size_t big = ((size_t)E * 4 > (size_t)N * 128) ? (size_t)E * 4 : (size_t)N * 128;
  unsigned* binbuf = (unsigned*)alloc(big);             // aliases h (dead before gemm1)
  uint2* h = (uint2*)binbuf;
  ushort_t* wt1 = (ushort_t*)alloc((size_t)2 * 64 * 256 * 2);  // 64 KB split W1
  ushort_t* wt2 = (ushort_t*)alloc((size_t)2 * 64 * 64 * 2);   // 16 KB split W2
  float* outf = (float*)d_out;

  zero_int<<<(nbins + 255) / 256, 256, 0, stream>>>(binCnt, nbins);
  bin_count<<<1024, 256, 0, stream>>>(dst, E, nbins, binCnt);
  bin_scan<<<1, 256, 0, stream>>>(binCnt, nbins, E, binStart, binCursor, supCursor);
  super_fill<<<(E + 2047) / 2048, 256, 0, stream>>>(src, dst, E, nsup, supCursor, supbuf);
  fine_fill<<<nsup * 8, 256, 0, stream>>>(supbuf, binStart, nbins, binCursor, binbuf);
  bin_csr<<<nbins, 256, 0, stream>>>(binbuf, binStart, N, E, rowptr, col, dis);
  wsplit<<<(256 * 64 + 64 * 64 + 255) / 256, 256, 0, stream>>>(W1, W2, wt1, wt2);

  gemm1_mfma<<<(N + 63) / 64, 256, 0, stream>>>(x, wt1, h, N);
  agg_kernel<true><<<(N + 3) / 4, 256, 0, stream>>>(h, rowptr, col, dis, b1, out1, N, 1);
  gemm2_mfma<<<(N + 63) / 64, 256, 0, stream>>>((const ushort_t*)out1, wt2, h, N);
  agg_kernel<false><<<(N + 3) / 4, 256, 0, stream>>>(h, rowptr, col, dis, b2, outf, N, 0);
}

// Round 11
// 453.645 us; speedup vs baseline: 1.0520x; 1.0520x over previous
//
#include <hip/hip_runtime.h>
#include <cstdint>
#include <cstddef>

// ---------------------------------------------------------------------------
// GCN 2-layer encoder.  Pipeline per launch (11 dispatches):
//   1. bin_count: 782-bin histogram of dst>>7
//   2. bin_scan:  binStart/binCursor (fine) + superCursor (dst>>11, 49 bins)
//   3. super_fill: partition edges into super-bins (1 tile/block)
//   4. fine_fill:  scatter each super-segment into its 16 fine bins
//   5. bin_csr: FUSED per-bin count + dis + scan + CSR col scatter
//   6. wsplit: W1/W2 -> transposed split-bf16 planes [2][64][K] (hi, lo)
//   7. gemm1_mfma -> h1 bf16: 64 NODES PER WAVE (4 m-tiles) -- weight-table
//      L2 traffic scales as 1/(nodes per wave): r9's 16 n/w = 400 MB = 76us,
//      r5's 32 n/w = 200 MB = 63us; this = 100 MB.  2-buffer LDS-DMA ring
//      (64 KB, 2 blocks/CU), weights issued before the DMA wait, ledger
//      vmcnt(16)/(8); lgkmcnt(0) guards the 2-buf read-vs-restage race.
//   8. agg1 -> out1 (bf16, relu)  [fabric-roofline ~2.8 TB/s, left as-is]
//   9. gemm2_mfma -> h2 bf16 (r8 shape: 32 n/w, A exact bf16, 2-term)
//  10. agg2 -> d_out (fp32)
// MFMA orientation: D[n][m] = Wt[n][k] * x[m][k]^T so each lane holds 4
// consecutive output cols of one node -> packs straight into uint2 bf16.
// ---------------------------------------------------------------------------

#define BIN_SHIFT 7
#define BIN_NODES 128
#define MAX_BINS 1024
#define SUP_SHIFT 11
#define FINE_PER_SUP 16
#define NSUP_MAX 64
#define SCAP 56  // per-super staging capacity per 2048-edge tile (mean 42)
#define SRC_BITS 17
#define SRC_MASK ((1 << SRC_BITS) - 1)

typedef unsigned short ushort_t;

typedef __attribute__((ext_vector_type(8))) short bf16x8;  // 8 bf16 (4 VGPRs)
typedef __attribute__((ext_vector_type(4))) float f32x4;   // MFMA accumulator

union FragB {
  uint4 u;
  bf16x8 b;
};

__device__ __forceinline__ float4 bfq2f4(uint2 p) {  // 4 packed bf16 -> fp32 (exact)
  float4 r;
  r.x = __uint_as_float(p.x << 16);
  r.y = __uint_as_float(p.x & 0xFFFF0000u);
  r.z = __uint_as_float(p.y << 16);
  r.w = __uint_as_float(p.y & 0xFFFF0000u);
  return r;
}
__device__ __forceinline__ unsigned f2bf(float f) {  // fp32 -> bf16 bits, RNE
  unsigned u = __float_as_uint(f);
  return (u + 0x7FFFu + ((u >> 16) & 1u)) >> 16;
}
__device__ __forceinline__ uint2 f42bfq(float4 f) {
  uint2 r;
  r.x = f2bf(f.x) | (f2bf(f.y) << 16);
  r.y = f2bf(f.z) | (f2bf(f.w) << 16);
  return r;
}

__global__ void zero_int(int* __restrict__ p, int n) {
  int i = blockIdx.x * blockDim.x + threadIdx.x;
  if (i < n) p[i] = 0;
}

// --- pass 1: fine histogram -------------------------------------------------
__global__ __launch_bounds__(256) void bin_count(const int* __restrict__ dst, int E, int nbins,
                                                 int* __restrict__ binCnt) {
  __shared__ int h[MAX_BINS];
  for (int i = threadIdx.x; i < nbins; i += 256) h[i] = 0;
  __syncthreads();
  int stride = gridDim.x * 256;
  for (int e = blockIdx.x * 256 + threadIdx.x; e < E; e += stride)
    atomicAdd(&h[dst[e] >> BIN_SHIFT], 1);
  __syncthreads();
  for (int i = threadIdx.x; i < nbins; i += 256)
    if (h[i]) atomicAdd(&binCnt[i], h[i]);
}

// --- pass 2: scan fine bins; derive super cursors ---------------------------
__global__ __launch_bounds__(256) void bin_scan(const int* __restrict__ binCnt, int nbins, int E,
                                                int* __restrict__ binStart,
                                                int* __restrict__ binCursor,
                                                int* __restrict__ supCursor) {
  __shared__ int s[256];
  int t = threadIdx.x;
  int c[4];
  int sum = 0;
#pragma unroll
  for (int i = 0; i < 4; i++) {
    int idx = t * 4 + i;
    c[i] = (idx < nbins) ? binCnt[idx] : 0;
    sum += c[i];
  }
  int v = sum;
  s[t] = v;
  __syncthreads();
  for (int d = 1; d < 256; d <<= 1) {
    int add = (t >= d) ? s[t - d] : 0;
    __syncthreads();
    s[t] += add;
    __syncthreads();
  }
  int run = s[t] - v;  // exclusive prefix
#pragma unroll
  for (int i = 0; i < 4; i++) {
    int idx = t * 4 + i;
    if (idx < nbins) {
      binStart[idx] = run;
      binCursor[idx] = run;
      if ((idx & (FINE_PER_SUP - 1)) == 0) supCursor[idx >> 4] = run;  // super segment start
      run += c[i];
    }
  }
  if (t == 0) binStart[nbins] = E;
}

// --- pass 3: partition into super-bins, one 2048-edge tile per block --------
__global__ __launch_bounds__(256) void super_fill(const int* __restrict__ src,
                                                  const int* __restrict__ dst, int E, int nsup,
                                                  int* __restrict__ supCursor,
                                                  unsigned* __restrict__ supbuf) {
  __shared__ unsigned stage[NSUP_MAX * SCAP];
  __shared__ int lcnt[NSUP_MAX], lbase[NSUP_MAX], lscan[NSUP_MAX + 1];
  const int tid = threadIdx.x;
  const int t0 = blockIdx.x * 2048;
  const int t1 = min(E, t0 + 2048);

  int dv[8], sv[8];
#pragma unroll
  for (int i = 0; i < 8; i++) {
    int e = t0 + i * 256 + tid;
    if (e < t1) {
      dv[i] = dst[e];
      sv[i] = src[e];
    }
  }
  if (tid < nsup) lcnt[tid] = 0;
  __syncthreads();
#pragma unroll
  for (int i = 0; i < 8; i++) {
    int e = t0 + i * 256 + tid;
    if (e < t1) {
      int d = dv[i];
      int sb = d >> SUP_SHIFT;
      unsigned v = ((unsigned)(d & ((1 << SUP_SHIFT) - 1)) << SRC_BITS) | (unsigned)sv[i];
      int idx = atomicAdd(&lcnt[sb], 1);
      if (idx < SCAP)
        stage[sb * SCAP + idx] = v;
      else {  // rare overflow: direct write
        int g = atomicAdd(&supCursor[sb], 1);
        supbuf[g] = v;
      }
    }
  }
  __syncthreads();
  if (tid < nsup) {
    int c = min(lcnt[tid], SCAP);
    lcnt[tid] = c;
    lbase[tid] = c ? atomicAdd(&supCursor[tid], c) : 0;
  }
  __syncthreads();
  if (tid < 64) {  // wave-0 inclusive scan over 64 bins
    int vv = (tid < nsup) ? lcnt[tid] : 0;
    int ss = vv;
#pragma unroll
    for (int d = 1; d < 64; d <<= 1) {
      int u = __shfl_up(ss, d);
      if (tid >= d) ss += u;
    }
    lscan[tid + 1] = ss;
    if (tid == 0) lscan[0] = 0;
  }
  __syncthreads();
  int total = lscan[nsup];
  for (int j = tid; j < total; j += 256) {
    int lo = 0, hi = nsup;  // binary search: lscan[lo] <= j < lscan[lo+1]
    while (hi - lo > 1) {
      int mid = (lo + hi) >> 1;
      if (lscan[mid] <= j)
        lo = mid;
      else
        hi = mid;
    }
    int off = j - lscan[lo];
    supbuf[lbase[lo] + off] = stage[lo * SCAP + off];
  }
}

// --- pass 4: scatter super-segment into its 16 fine bins (L2 window) --------
__global__ __launch_bounds__(256) void fine_fill(const unsigned* __restrict__ supbuf,
                                                 const int* __restrict__ binStart, int nbins,
                                                 int* __restrict__ binCursor,
                                                 unsigned* __restrict__ binbuf) {
  __shared__ int lcnt[FINE_PER_SUP], lbase[FINE_PER_SUP];
  int sb = blockIdx.x >> 3, p = blockIdx.x & 7;
  int seg0 = binStart[sb << 4];
  int seg1 = binStart[min((sb + 1) << 4, nbins)];
  int part = (seg1 - seg0 + 7) >> 3;
  int c0 = seg0 + p * part;
  int c1 = min(seg1, c0 + part);
  if (threadIdx.x < FINE_PER_SUP) lcnt[threadIdx.x] = 0;
  __syncthreads();
  for (int i = c0 + threadIdx.x; i < c1; i += 256) atomicAdd(&lcnt[supbuf[i] >> 24], 1);
  __syncthreads();
  if (threadIdx.x < FINE_PER_SUP) {
    int c = lcnt[threadIdx.x];
    lbase[threadIdx.x] = c ? atomicAdd(&binCursor[(sb << 4) + threadIdx.x], c) : 0;
    lcnt[threadIdx.x] = 0;
  }
  __syncthreads();
  for (int i = c0 + threadIdx.x; i < c1; i += 256) {
    unsigned v = supbuf[i];
    unsigned dls = v >> SRC_BITS;  // 11-bit dst-local-to-super
    int f = dls >> BIN_SHIFT;      // fine bin within super
    unsigned vf = ((dls & (BIN_NODES - 1)) << SRC_BITS) | (v & SRC_MASK);
    int idx = lbase[f] + atomicAdd(&lcnt[f], 1);
    binbuf[idx] = vf;
  }
}

// --- pass 5: FUSED per-bin count + dis + scan + CSR col scatter -------------
__global__ __launch_bounds__(256) void bin_csr(const unsigned* __restrict__ binbuf,
                                               const int* __restrict__ binStart, int N, int E,
                                               int* __restrict__ rowptr, int* __restrict__ col,
                                               float* __restrict__ dis) {
  __shared__ int cnt[BIN_NODES];
  __shared__ int cur[BIN_NODES];
  __shared__ int pref[BIN_NODES];
  int b = blockIdx.x, t = threadIdx.x;
  int nodeBase = b << BIN_SHIFT;
  if (t < BIN_NODES) cnt[t] = 0;
  __syncthreads();
  int s0 = binStart[b], s1 = binStart[b + 1];
  for (int i = s0 + t; i < s1; i += 256) atomicAdd(&cnt[binbuf[i] >> SRC_BITS], 1);
  __syncthreads();
  int c = 0;
  if (t < BIN_NODES) {
    int node = nodeBase + t;
    if (node < N) {
      c = cnt[t];
      dis[node] = rsqrtf((float)(c + 1));  // +1 self loop
    }
    pref[t] = c;
  }
  __syncthreads();
  for (int d = 1; d < BIN_NODES; d <<= 1) {  // inclusive scan over 128
    int add = (t < BIN_NODES && t >= d) ? pref[t - d] : 0;
    __syncthreads();
    if (t < BIN_NODES) pref[t] += add;
    __syncthreads();
  }
  if (t < BIN_NODES) {
    int node = nodeBase + t;
    if (node < N) {
      int ex = s0 + pref[t] - c;  // exclusive prefix + segment base
      rowptr[node] = ex;
      cur[t] = ex;
    }
  }
  if (b == 0 && t == 255) rowptr[N] = E;
  __syncthreads();
  for (int i = s0 + t; i < s1; i += 256) {  // second read: L2-hot segment
    unsigned v = binbuf[i];
    int slot = atomicAdd(&cur[v >> SRC_BITS], 1);
    col[slot] = v & SRC_MASK;
  }
}

// --- pass 6: split W1/W2 into transposed bf16 hi/lo planes ------------------
__global__ __launch_bounds__(256) void wsplit(const float* __restrict__ W1,
                                              const float* __restrict__ W2,
                                              ushort_t* __restrict__ wt1,
                                              ushort_t* __restrict__ wt2) {
  int i = blockIdx.x * 256 + threadIdx.x;
  const float* W;
  ushort_t* wt;
  int K, idx;
  if (i < 256 * 64) {
    W = W1; wt = wt1; K = 256; idx = i;
  } else if (i < 256 * 64 + 64 * 64) {
    W = W2; wt = wt2; K = 64; idx = i - 256 * 64;
  } else
    return;
  int n = idx & 63, k = idx >> 6;
  float f = W[k * 64 + n];  // W is [K][64] row-major
  unsigned u = __float_as_uint(f);
  unsigned hb = u & 0xFFFF0000u;
  float lo = f - __uint_as_float(hb);
  wt[(size_t)n * K + k] = (ushort_t)(u >> 16);
  wt[(size_t)64 * K + (size_t)n * K + k] = (ushort_t)(__float_as_uint(lo) >> 16);
}

// split 8 packed fp32 (as 2 uint4) into bf16 hi (truncate) + lo (trunc resid)
__device__ __forceinline__ void split8u(uint4 a, uint4 b, uint4& xh, uint4& xl) {
  unsigned ua[8] = {a.x, a.y, a.z, a.w, b.x, b.y, b.z, b.w};
  unsigned hw[4], lw[4];
#pragma unroll
  for (int p = 0; p < 4; p++) {
    unsigned u0 = ua[2 * p], u1 = ua[2 * p + 1];
    unsigned h0 = u0 & 0xFFFF0000u, h1 = u1 & 0xFFFF0000u;
    float l0 = __uint_as_float(u0) - __uint_as_float(h0);
    float l1 = __uint_as_float(u1) - __uint_as_float(h1);
    hw[p] = (u0 >> 16) | h1;
    lw[p] = (__float_as_uint(l0) >> 16) | (__float_as_uint(l1) & 0xFFFF0000u);
  }
  xh = make_uint4(hw[0], hw[1], hw[2], hw[3]);
  xl = make_uint4(lw[0], lw[1], lw[2], lw[3]);
}

// --- gemm1: Cbf16[M][64] = x[M][256] @ W1, 64 nodes/wave, 2-buf LDS ring ----
// Block = 256 nodes (4 waves x 64).  Per 32-wide k-tile a wave DMAs its 64
// rows (8 KB, 8 calls) into a 2-buffer ring (64 KB LDS -> 2 blocks/CU).
// Each weight fragment load now feeds 4 m-tiles (48 MFMA : 8 loads) --
// weight-table L2 traffic = 100 MB vs r5's 200 / r9's 400 (the measured
// 1/(nodes-per-wave) scaling is the dominant gemm1 cost).
// Ledger: entering iter j (after issuing w:8): [st(j):8, st(j+1):8 (j<7),
// w:8] -> vmcnt(16) drains st(j) (j=7: vmcnt(8)).  lgkmcnt(0) before
// re-staging buf j&1 guards the 2-buf read/overwrite race.  No barriers.
__global__ __launch_bounds__(256, 2) void gemm1_mfma(const float* __restrict__ A,
                                                     const ushort_t* __restrict__ Wt,
                                                     uint2* __restrict__ Cb, int M) {
  constexpr int K = 256;
  __shared__ uint4 xtile[2][4][512];  // [ring buf][wave][slot] = 64 KB
  const int lane = threadIdx.x & 63;
  const int wv = threadIdx.x >> 6;
  const int l15 = lane & 15;
  const int lq = lane >> 4;
  const int m0 = blockIdx.x * 256 + wv * 64;

  const ushort_t* __restrict__ Wlo = Wt + (size_t)64 * K;

  f32x4 acc[4][4];  // [mt][nt] = 64 VGPRs
#pragma unroll
  for (int a = 0; a < 4; a++)
#pragma unroll
    for (int b = 0; b < 4; b++) acc[a][b] = (f32x4){0.f, 0.f, 0.f, 0.f};

  // stage tile kt into ring buffer buf (this wave's 64 rows, 8 KB, 8 calls)
  auto stage_tile = [&](int kt, int buf) {
#pragma unroll
    for (int c = 0; c < 8; c++) {
      int s = c * 64 + lane;           // 0..511
      int r = s >> 3;                  // row 0..63 within wave block
      int c4 = (s & 7) ^ (r & 7);      // swizzled float4-column
      int nd = m0 + r;
      if (nd >= M) nd = M - 1;
      const float* gp = A + (size_t)nd * K + kt * 32 + c4 * 4;
      __builtin_amdgcn_global_load_lds(
          (const __attribute__((address_space(1))) void*)gp,
          (__attribute__((address_space(3))) void*)&xtile[buf][wv][c * 64], 16, 0, 0);
    }
  };

  // prologue: st(0), st(1)
  stage_tile(0, 0);
  stage_tile(1, 1);
  __builtin_amdgcn_sched_barrier(0);

#pragma unroll
  for (int j = 0; j < 8; j++) {
    // a. issue this iteration's weight loads FIRST (L2 latency overlaps wait)
    FragB w[8];
    {
      const int kb = j * 32 + lq * 8;
#pragma unroll
      for (int nt = 0; nt < 4; nt++) {
        w[nt].u = *(const uint4*)(Wt + (size_t)(nt * 16 + l15) * K + kb);
        w[4 + nt].u = *(const uint4*)(Wlo + (size_t)(nt * 16 + l15) * K + kb);
      }
    }
    __builtin_amdgcn_sched_barrier(0);
    // b. ensure tile j staged: queue=[st(j):8, st(j+1):8 (j<7), w:8]
    if (j < 7)
      asm volatile("s_waitcnt vmcnt(16)" ::: "memory");
    else
      asm volatile("s_waitcnt vmcnt(8)" ::: "memory");
    __builtin_amdgcn_sched_barrier(0);
    // c. ds_read tile j fragments (swizzled), 4 m-tiles x 2 halves
    uint4 xa[4][2];
#pragma unroll
    for (int mt = 0; mt < 4; mt++) {
      int mr = mt * 16 + l15;
#pragma unroll
      for (int hh = 0; hh < 2; hh++) {
        int c4 = (lq * 2 + hh) ^ (mr & 7);
        xa[mt][hh] = *(const uint4*)&xtile[j & 1][wv][mr * 8 + c4];
      }
    }
    __builtin_amdgcn_sched_barrier(0);
    // d. reads must COMPLETE before re-staging this buffer (2-buf race guard)
    asm volatile("s_waitcnt lgkmcnt(0)" ::: "memory");
    __builtin_amdgcn_sched_barrier(0);
    if (j + 2 < 8) stage_tile(j + 2, j & 1);
    __builtin_amdgcn_sched_barrier(0);
    // e. per m-tile: split + 12 MFMA (compiler w-wait = vmcnt(8))
#pragma unroll
    for (int mt = 0; mt < 4; mt++) {
      FragB xh, xl;
      split8u(xa[mt][0], xa[mt][1], xh.u, xl.u);
#pragma unroll
      for (int nt = 0; nt < 4; nt++) {
        acc[mt][nt] = __builtin_amdgcn_mfma_f32_16x16x32_bf16(w[nt].b, xh.b, acc[mt][nt], 0, 0, 0);
        acc[mt][nt] = __builtin_amdgcn_mfma_f32_16x16x32_bf16(w[nt].b, xl.b, acc[mt][nt], 0, 0, 0);
      }
#pragma unroll
      for (int nt = 0; nt < 4; nt++) {
        acc[mt][nt] =
            __builtin_amdgcn_mfma_f32_16x16x32_bf16(w[4 + nt].b, xh.b, acc[mt][nt], 0, 0, 0);
      }
    }
  }

#pragma unroll
  for (int mt = 0; mt < 4; mt++) {
    int node = m0 + mt * 16 + l15;
    if (node < M) {
      uint2* cp = Cb + (size_t)node * 16 + lq;
#pragma unroll
      for (int nt = 0; nt < 4; nt++) {
        float4 o = make_float4(acc[mt][nt][0], acc[mt][nt][1], acc[mt][nt][2], acc[mt][nt][3]);
        cp[nt * 4] = f42bfq(o);  // cols nt*16 + lq*4 .. +3
      }
    }
  }
}

// --- gemm2: Cbf16[M][64] = out1[M][64] @ W2 (32 n/w, A exact bf16, 2-term) --
__global__ __launch_bounds__(256, 3) void gemm2_mfma(const ushort_t* __restrict__ Av,
                                                     const ushort_t* __restrict__ Wt,
                                                     uint2* __restrict__ Cb, int M) {
  constexpr int K = 64;
  constexpr int NT = K / 32;  // 2
  const int lane = threadIdx.x & 63;
  const int wv = threadIdx.x >> 6;
  const int l15 = lane & 15;
  const int lq = lane >> 4;
  const int m0 = blockIdx.x * 128 + wv * 32;

  const ushort_t* __restrict__ Wlo = Wt + (size_t)64 * K;

  f32x4 acc[2][4];
#pragma unroll
  for (int a = 0; a < 2; a++)
#pragma unroll
    for (int b = 0; b < 4; b++) acc[a][b] = (f32x4){0.f, 0.f, 0.f, 0.f};

  int node[2], ncl[2];
#pragma unroll
  for (int mt = 0; mt < 2; mt++) {
    node[mt] = m0 + mt * 16 + l15;
    ncl[mt] = node[mt] < M ? node[mt] : (M - 1);
  }

  FragB xa[NT][2], wh[NT][4], wl[NT][4];
#pragma unroll
  for (int t = 0; t < NT; t++)
#pragma unroll
    for (int mt = 0; mt < 2; mt++)
      xa[t][mt].u = *(const uint4*)(Av + (size_t)ncl[mt] * K + t * 32 + lq * 8);
#pragma unroll
  for (int t = 0; t < NT; t++)
#pragma unroll
    for (int nt = 0; nt < 4; nt++) {
      wh[t][nt].u = *(const uint4*)(Wt + (size_t)(nt * 16 + l15) * K + t * 32 + lq * 8);
      wl[t][nt].u = *(const uint4*)(Wlo + (size_t)(nt * 16 + l15) * K + t * 32 + lq * 8);
    }
#pragma unroll
  for (int t = 0; t < NT; t++)
#pragma unroll
    for (int mt = 0; mt < 2; mt++)
#pragma unroll
      for (int nt = 0; nt < 4; nt++) {
        acc[mt][nt] =
            __builtin_amdgcn_mfma_f32_16x16x32_bf16(wh[t][nt].b, xa[t][mt].b, acc[mt][nt], 0, 0, 0);
        acc[mt][nt] =
            __builtin_amdgcn_mfma_f32_16x16x32_bf16(wl[t][nt].b, xa[t][mt].b, acc[mt][nt], 0, 0, 0);
      }

#pragma unroll
  for (int mt = 0; mt < 2; mt++) {
    if (node[mt] < M) {
      uint2* cp = Cb + (size_t)node[mt] * 16 + lq;
#pragma unroll
      for (int nt = 0; nt < 4; nt++) {
        float4 o = make_float4(acc[mt][nt][0], acc[mt][nt][1], acc[mt][nt][2], acc[mt][nt][3]);
        cp[nt * 4] = f42bfq(o);
      }
    }
  }
}

// --- aggregation: wave per node, depth-4 rolling gather pipeline ------------
// Fabric-roofline-bound (~165 MB L2-miss @ ~2.8 TB/s); structure kept.
template <bool OUTBF>
__global__ __launch_bounds__(256) void agg_kernel(
    const uint2* __restrict__ h, const int* __restrict__ rowptr, const int* __restrict__ col,
    const float* __restrict__ dis, const float* __restrict__ bias, void* __restrict__ outv,
    int N, int relu) {
  int wid = (blockIdx.x * blockDim.x + threadIdx.x) >> 6;
  if (wid >= N) return;
  int lane = threadIdx.x & 63;
  int sub = lane & 15;
  int quarter = lane >> 4;

  int start = rowptr[wid], end = rowptr[wid + 1];
  float di = dis[wid];

  float4 a0 = make_float4(0.f, 0.f, 0.f, 0.f), a1 = a0, a2 = a0, a3 = a0;
  {  // self-loop: di*h_self (quarter 0 only); final *di makes it di^2
    float4 self = bfq2f4(h[(size_t)wid * 16 + sub]);
    if (quarter == 0) {
      a0.x = di * self.x;
      a0.y = di * self.y;
      a0.z = di * self.z;
      a0.w = di * self.w;
    }
  }

  for (int base = start; base < end; base += 64) {
    int e = base + lane;
    int sj = 0;
    float wj = 0.f;
    if (e < end) {
      sj = col[e];
      wj = dis[sj];  // L2-resident 400 KB table
    }
    int cnt = end - base;
    if (cnt > 64) cnt = 64;
    int rounds = (cnt + 3) >> 2;  // wave-uniform

    uint2 g0, g1, g2, g3;
    float w0, w1, w2, w3;
#define ISSUE(gi, G, W)                                              \
  do {                                                               \
    int _i = (4 * (gi) + quarter) & 63;                              \
    int _s = __shfl(sj, _i);                                         \
    float _w = __shfl(wj, _i);                                       \
    if ((gi) < rounds) {                                             \
      G = h[(size_t)_s * 16 + sub];                                  \
      W = _w;                                                        \
    } else {                                                         \
      G = make_uint2(0u, 0u);                                        \
      W = 0.f;                                                       \
    }                                                                \
  } while (0)

    ISSUE(0, g0, w0);
    ISSUE(1, g1, w1);
    ISSUE(2, g2, w2);
    ISSUE(3, g3, w3);
    int rounds4 = (rounds + 3) & ~3;
    for (int t0 = 0; t0 < rounds4; t0 += 4) {
      {
        float4 gf = bfq2f4(g0);
        a0.x += w0 * gf.x; a0.y += w0 * gf.y; a0.z += w0 * gf.z; a0.w += w0 * gf.w;
      }
      ISSUE(t0 + 4, g0, w0);
      {
        float4 gf = bfq2f4(g1);
        a1.x += w1 * gf.x; a1.y += w1 * gf.y; a1.z += w1 * gf.z; a1.w += w1 * gf.w;
      }
      ISSUE(t0 + 5, g1, w1);
      {
        float4 gf = bfq2f4(g2);
        a2.x += w2 * gf.x; a2.y += w2 * gf.y; a2.z += w2 * gf.z; a2.w += w2 * gf.w;
      }
      ISSUE(t0 + 6, g2, w2);
      {
        float4 gf = bfq2f4(g3);
        a3.x += w3 * gf.x; a3.y += w3 * gf.y; a3.z += w3 * gf.z; a3.w += w3 * gf.w;
      }
      ISSUE(t0 + 7, g3, w3);
    }
#undef ISSUE
  }

  float sx = (a0.x + a1.x) + (a2.x + a3.x);
  float sy = (a0.y + a1.y) + (a2.y + a3.y);
  float sz = (a0.z + a1.z) + (a2.z + a3.z);
  float sw = (a0.w + a1.w) + (a2.w + a3.w);
  sx += __shfl_down(sx, 32); sy += __shfl_down(sy, 32);
  sz += __shfl_down(sz, 32); sw += __shfl_down(sw, 32);
  sx += __shfl_down(sx, 16); sy += __shfl_down(sy, 16);
  sz += __shfl_down(sz, 16); sw += __shfl_down(sw, 16);
  if (quarter == 0) {
    float4 bv = ((const float4*)bias)[sub];
    float4 o = make_float4(di * sx + bv.x, di * sy + bv.y, di * sz + bv.z, di * sw + bv.w);
    if (relu) {
      o.x = fmaxf(o.x, 0.f);
      o.y = fmaxf(o.y, 0.f);
      o.z = fmaxf(o.z, 0.f);
      o.w = fmaxf(o.w, 0.f);
    }
    if (OUTBF)
      ((uint2*)outv)[(size_t)wid * 16 + sub] = f42bfq(o);
    else
      ((float4*)outv)[(size_t)wid * 16 + sub] = o;
  }
}

// ---------------------------------------------------------------------------
extern "C" void kernel_launch(void* const* d_in, const int* in_sizes, int n_in,
                              void* d_out, int out_size, void* d_ws, size_t ws_size,
                              hipStream_t stream) {
  const float* x = (const float*)d_in[0];
  const int* ei = (const int*)d_in[1];
  const float* W1 = (const float*)d_in[2];
  const float* b1 = (const float*)d_in[3];
  const float* W2 = (const float*)d_in[4];
  const float* b2 = (const float*)d_in[5];

  const int IN = 256;
  const int E = in_sizes[1] / 2;
  const int N = in_sizes[0] / IN;
  const int* src = ei;
  const int* dst = ei + E;
  const int nbins = (N + BIN_NODES - 1) >> BIN_SHIFT;
  const int nsup = (N + (1 << SUP_SHIFT) - 1) >> SUP_SHIFT;

  // workspace carve-up (256B aligned)
  char* ws = (char*)d_ws;
  size_t off = 0;
  auto alloc = [&](size_t bytes) -> void* {
    void* p = ws + off;
    off += (bytes + 255) & ~(size_t)255;
    return p;
  };
  int* rowptr = (int*)alloc((size_t)(N + 1) * 4);
  float* dis = (float*)alloc((size_t)N * 4);
  int* binCnt = (int*)alloc(MAX_BINS * 4);
  int* binStart = (int*)alloc((MAX_BINS + 1) * 4);
  int* binCursor = (int*)alloc(MAX_BINS * 4);
  int* supCursor = (int*)alloc(NSUP_MAX * 4);
  int* col = (int*)alloc((size_t)E * 4);                // 12.8 MB; written by bin_csr
  unsigned* supbuf = (unsigned*)col;                    // alias: dead before col written
  uint2* out1 = (uint2*)alloc((size_t)N * 64 * 2);      // bf16 layer-1 activations
  size_t big = ((size_t)E * 4 > (size_t)N * 128) ? (size_t)E * 4 : (size_t)N * 128;
  unsigned* binbuf = (unsigned*)alloc(big);             // aliases h (dead before gemm1)
  uint2* h = (uint2*)binbuf;
  ushort_t* wt1 = (ushort_t*)alloc((size_t)2 * 64 * 256 * 2);  // 64 KB split W1
  ushort_t* wt2 = (ushort_t*)alloc((size_t)2 * 64 * 64 * 2);   // 16 KB split W2
  float* outf = (float*)d_out;

  zero_int<<<(nbins + 255) / 256, 256, 0, stream>>>(binCnt, nbins);
  bin_count<<<1024, 256, 0, stream>>>(dst, E, nbins, binCnt);
  bin_scan<<<1, 256, 0, stream>>>(binCnt, nbins, E, binStart, binCursor, supCursor);
  super_fill<<<(E + 2047) / 2048, 256, 0, stream>>>(src, dst, E, nsup, supCursor, supbuf);
  fine_fill<<<nsup * 8, 256, 0, stream>>>(supbuf, binStart, nbins, binCursor, binbuf);
  bin_csr<<<nbins, 256, 0, stream>>>(binbuf, binStart, N, E, rowptr, col, dis);
  wsplit<<<(256 * 64 + 64 * 64 + 255) / 256, 256, 0, stream>>>(W1, W2, wt1, wt2);

  gemm1_mfma<<<(N + 255) / 256, 256, 0, stream>>>(x, wt1, h, N);
  agg_kernel<true><<<(N + 3) / 4, 256, 0, stream>>>(h, rowptr, col, dis, b1, out1, N, 1);
  gemm2_mfma<<<(N + 127) / 128, 256, 0, stream>>>((const ushort_t*)out1, wt2, h, N);
  agg_kernel<false><<<(N + 3) / 4, 256, 0, stream>>>(h, rowptr, col, dis, b2, outf, N, 0);
}

// Round 12
// 447.427 us; speedup vs baseline: 1.0666x; 1.0139x over previous
//
#include <hip/hip_runtime.h>
#include <cstdint>
#include <cstddef>

// ---------------------------------------------------------------------------
// GCN 2-layer encoder.  Pipeline per launch (10 dispatches):
//   1. prep: zero binCnt + wsplit (W1/W2 -> transposed split-bf16 hi/lo)
//   2. bin_count: 782-bin histogram of dst>>7
//   3. bin_scan:  binStart/binCursor (fine) + superCursor (dst>>11, 49 bins)
//   4. super_fill: partition edges into super-bins (1 tile/block)
//   5. fine_fill:  scatter each super-segment into its 16 fine bins
//   6. bin_csr: FUSED per-bin count + dis + scan + CSR col scatter
//   7. gemm1_mfma -> h1 bf16: 64 n/w + W TABLE IN LDS (64 KB, XOR-swizzled)
//      -- kills the per-wave 64 KB L2 weight re-stream (was 100 MB chip-wide;
//      measured 1/(n per wave) scaling: 400/200/100 MB -> 76/63/<63 us).
//      128 KB LDS total (1 block/CU); x-ring ledger vmcnt(8)/(0).
//   8. agg1 -> out1 (bf16, relu)  [fabric-roofline ~2.8 TB/s, left as-is]
//   9. gemm2_mfma -> h2 bf16 (32 n/w, W2 in LDS 16 KB, A exact bf16)
//  10. agg2 -> d_out (fp32)
// MFMA orientation: D[n][m] = Wt[n][k] * x[m][k]^T so each lane holds 4
// consecutive output cols of one node -> packs straight into uint2 bf16.
// ---------------------------------------------------------------------------

#define BIN_SHIFT 7
#define BIN_NODES 128
#define MAX_BINS 1024
#define SUP_SHIFT 11
#define FINE_PER_SUP 16
#define NSUP_MAX 64
#define SCAP 56  // per-super staging capacity per 2048-edge tile (mean 42)
#define SRC_BITS 17
#define SRC_MASK ((1 << SRC_BITS) - 1)

typedef unsigned short ushort_t;

typedef __attribute__((ext_vector_type(8))) short bf16x8;  // 8 bf16 (4 VGPRs)
typedef __attribute__((ext_vector_type(4))) float f32x4;   // MFMA accumulator

union FragB {
  uint4 u;
  bf16x8 b;
};

__device__ __forceinline__ float4 bfq2f4(uint2 p) {  // 4 packed bf16 -> fp32 (exact)
  float4 r;
  r.x = __uint_as_float(p.x << 16);
  r.y = __uint_as_float(p.x & 0xFFFF0000u);
  r.z = __uint_as_float(p.y << 16);
  r.w = __uint_as_float(p.y & 0xFFFF0000u);
  return r;
}
__device__ __forceinline__ unsigned f2bf(float f) {  // fp32 -> bf16 bits, RNE
  unsigned u = __float_as_uint(f);
  return (u + 0x7FFFu + ((u >> 16) & 1u)) >> 16;
}
__device__ __forceinline__ uint2 f42bfq(float4 f) {
  uint2 r;
  r.x = f2bf(f.x) | (f2bf(f.y) << 16);
  r.y = f2bf(f.z) | (f2bf(f.w) << 16);
  return r;
}

// --- pass 1: prep = zero binCnt + wsplit ------------------------------------
// wt layout: [plane(hi=0,lo=1)][n(64)][k(K)] bf16.  hi = truncation,
// lo = bf16_trunc(w - hi_as_f32); hi+lo represents w to ~2^-16 relative.
__global__ __launch_bounds__(256) void prep(const float* __restrict__ W1,
                                            const float* __restrict__ W2,
                                            ushort_t* __restrict__ wt1,
                                            ushort_t* __restrict__ wt2,
                                            int* __restrict__ binCnt, int nbins) {
  int i = blockIdx.x * 256 + threadIdx.x;
  if (i < nbins) binCnt[i] = 0;
  const float* W;
  ushort_t* wt;
  int K, idx;
  if (i < 256 * 64) {
    W = W1; wt = wt1; K = 256; idx = i;
  } else if (i < 256 * 64 + 64 * 64) {
    W = W2; wt = wt2; K = 64; idx = i - 256 * 64;
  } else
    return;
  int n = idx & 63, k = idx >> 6;
  float f = W[k * 64 + n];  // W is [K][64] row-major
  unsigned u = __float_as_uint(f);
  unsigned hb = u & 0xFFFF0000u;
  float lo = f - __uint_as_float(hb);
  wt[(size_t)n * K + k] = (ushort_t)(u >> 16);
  wt[(size_t)64 * K + (size_t)n * K + k] = (ushort_t)(__float_as_uint(lo) >> 16);
}

// --- pass 2: fine histogram -------------------------------------------------
__global__ __launch_bounds__(256) void bin_count(const int* __restrict__ dst, int E, int nbins,
                                                 int* __restrict__ binCnt) {
  __shared__ int h[MAX_BINS];
  for (int i = threadIdx.x; i < nbins; i += 256) h[i] = 0;
  __syncthreads();
  int stride = gridDim.x * 256;
  for (int e = blockIdx.x * 256 + threadIdx.x; e < E; e += stride)
    atomicAdd(&h[dst[e] >> BIN_SHIFT], 1);
  __syncthreads();
  for (int i = threadIdx.x; i < nbins; i += 256)
    if (h[i]) atomicAdd(&binCnt[i], h[i]);
}

// --- pass 3: scan fine bins; derive super cursors ---------------------------
__global__ __launch_bounds__(256) void bin_scan(const int* __restrict__ binCnt, int nbins, int E,
                                                int* __restrict__ binStart,
                                                int* __restrict__ binCursor,
                                                int* __restrict__ supCursor) {
  __shared__ int s[256];
  int t = threadIdx.x;
  int c[4];
  int sum = 0;
#pragma unroll
  for (int i = 0; i < 4; i++) {
    int idx = t * 4 + i;
    c[i] = (idx < nbins) ? binCnt[idx] : 0;
    sum += c[i];
  }
  int v = sum;
  s[t] = v;
  __syncthreads();
  for (int d = 1; d < 256; d <<= 1) {
    int add = (t >= d) ? s[t - d] : 0;
    __syncthreads();
    s[t] += add;
    __syncthreads();
  }
  int run = s[t] - v;  // exclusive prefix
#pragma unroll
  for (int i = 0; i < 4; i++) {
    int idx = t * 4 + i;
    if (idx < nbins) {
      binStart[idx] = run;
      binCursor[idx] = run;
      if ((idx & (FINE_PER_SUP - 1)) == 0) supCursor[idx >> 4] = run;  // super segment start
      run += c[i];
    }
  }
  if (t == 0) binStart[nbins] = E;
}

// --- pass 4: partition into super-bins, one 2048-edge tile per block --------
__global__ __launch_bounds__(256) void super_fill(const int* __restrict__ src,
                                                  const int* __restrict__ dst, int E, int nsup,
                                                  int* __restrict__ supCursor,
                                                  unsigned* __restrict__ supbuf) {
  __shared__ unsigned stage[NSUP_MAX * SCAP];
  __shared__ int lcnt[NSUP_MAX], lbase[NSUP_MAX], lscan[NSUP_MAX + 1];
  const int tid = threadIdx.x;
  const int t0 = blockIdx.x * 2048;
  const int t1 = min(E, t0 + 2048);

  int dv[8], sv[8];
#pragma unroll
  for (int i = 0; i < 8; i++) {
    int e = t0 + i * 256 + tid;
    if (e < t1) {
      dv[i] = dst[e];
      sv[i] = src[e];
    }
  }
  if (tid < nsup) lcnt[tid] = 0;
  __syncthreads();
#pragma unroll
  for (int i = 0; i < 8; i++) {
    int e = t0 + i * 256 + tid;
    if (e < t1) {
      int d = dv[i];
      int sb = d >> SUP_SHIFT;
      unsigned v = ((unsigned)(d & ((1 << SUP_SHIFT) - 1)) << SRC_BITS) | (unsigned)sv[i];
      int idx = atomicAdd(&lcnt[sb], 1);
      if (idx < SCAP)
        stage[sb * SCAP + idx] = v;
      else {  // rare overflow: direct write
        int g = atomicAdd(&supCursor[sb], 1);
        supbuf[g] = v;
      }
    }
  }
  __syncthreads();
  if (tid < nsup) {
    int c = min(lcnt[tid], SCAP);
    lcnt[tid] = c;
    lbase[tid] = c ? atomicAdd(&supCursor[tid], c) : 0;
  }
  __syncthreads();
  if (tid < 64) {  // wave-0 inclusive scan over 64 bins
    int vv = (tid < nsup) ? lcnt[tid] : 0;
    int ss = vv;
#pragma unroll
    for (int d = 1; d < 64; d <<= 1) {
      int u = __shfl_up(ss, d);
      if (tid >= d) ss += u;
    }
    lscan[tid + 1] = ss;
    if (tid == 0) lscan[0] = 0;
  }
  __syncthreads();
  int total = lscan[nsup];
  for (int j = tid; j < total; j += 256) {
    int lo = 0, hi = nsup;  // binary search: lscan[lo] <= j < lscan[lo+1]
    while (hi - lo > 1) {
      int mid = (lo + hi) >> 1;
      if (lscan[mid] <= j)
        lo = mid;
      else
        hi = mid;
    }
    int off = j - lscan[lo];
    supbuf[lbase[lo] + off] = stage[lo * SCAP + off];
  }
}

// --- pass 5: scatter super-segment into its 16 fine bins (L2 window) --------
__global__ __launch_bounds__(256) void fine_fill(const unsigned* __restrict__ supbuf,
                                                 const int* __restrict__ binStart, int nbins,
                                                 int* __restrict__ binCursor,
                                                 unsigned* __restrict__ binbuf) {
  __shared__ int lcnt[FINE_PER_SUP], lbase[FINE_PER_SUP];
  int sb = blockIdx.x >> 3, p = blockIdx.x & 7;
  int seg0 = binStart[sb << 4];
  int seg1 = binStart[min((sb + 1) << 4, nbins)];
  int part = (seg1 - seg0 + 7) >> 3;
  int c0 = seg0 + p * part;
  int c1 = min(seg1, c0 + part);
  if (threadIdx.x < FINE_PER_SUP) lcnt[threadIdx.x] = 0;
  __syncthreads();
  for (int i = c0 + threadIdx.x; i < c1; i += 256) atomicAdd(&lcnt[supbuf[i] >> 24], 1);
  __syncthreads();
  if (threadIdx.x < FINE_PER_SUP) {
    int c = lcnt[threadIdx.x];
    lbase[threadIdx.x] = c ? atomicAdd(&binCursor[(sb << 4) + threadIdx.x], c) : 0;
    lcnt[threadIdx.x] = 0;
  }
  __syncthreads();
  for (int i = c0 + threadIdx.x; i < c1; i += 256) {
    unsigned v = supbuf[i];
    unsigned dls = v >> SRC_BITS;  // 11-bit dst-local-to-super
    int f = dls >> BIN_SHIFT;      // fine bin within super
    unsigned vf = ((dls & (BIN_NODES - 1)) << SRC_BITS) | (v & SRC_MASK);
    int idx = lbase[f] + atomicAdd(&lcnt[f], 1);
    binbuf[idx] = vf;
  }
}

// --- pass 6: FUSED per-bin count + dis + scan + CSR col scatter -------------
__global__ __launch_bounds__(256) void bin_csr(const unsigned* __restrict__ binbuf,
                                               const int* __restrict__ binStart, int N, int E,
                                               int* __restrict__ rowptr, int* __restrict__ col,
                                               float* __restrict__ dis) {
  __shared__ int cnt[BIN_NODES];
  __shared__ int cur[BIN_NODES];
  __shared__ int pref[BIN_NODES];
  int b = blockIdx.x, t = threadIdx.x;
  int nodeBase = b << BIN_SHIFT;
  if (t < BIN_NODES) cnt[t] = 0;
  __syncthreads();
  int s0 = binStart[b], s1 = binStart[b + 1];
  for (int i = s0 + t; i < s1; i += 256) atomicAdd(&cnt[binbuf[i] >> SRC_BITS], 1);
  __syncthreads();
  int c = 0;
  if (t < BIN_NODES) {
    int node = nodeBase + t;
    if (node < N) {
      c = cnt[t];
      dis[node] = rsqrtf((float)(c + 1));  // +1 self loop
    }
    pref[t] = c;
  }
  __syncthreads();
  for (int d = 1; d < BIN_NODES; d <<= 1) {  // inclusive scan over 128
    int add = (t < BIN_NODES && t >= d) ? pref[t - d] : 0;
    __syncthreads();
    if (t < BIN_NODES) pref[t] += add;
    __syncthreads();
  }
  if (t < BIN_NODES) {
    int node = nodeBase + t;
    if (node < N) {
      int ex = s0 + pref[t] - c;  // exclusive prefix + segment base
      rowptr[node] = ex;
      cur[t] = ex;
    }
  }
  if (b == 0 && t == 255) rowptr[N] = E;
  __syncthreads();
  for (int i = s0 + t; i < s1; i += 256) {  // second read: L2-hot segment
    unsigned v = binbuf[i];
    int slot = atomicAdd(&cur[v >> SRC_BITS], 1);
    col[slot] = v & SRC_MASK;
  }
}

// split 8 packed fp32 (as 2 uint4) into bf16 hi (truncate) + lo (trunc resid)
__device__ __forceinline__ void split8u(uint4 a, uint4 b, uint4& xh, uint4& xl) {
  unsigned ua[8] = {a.x, a.y, a.z, a.w, b.x, b.y, b.z, b.w};
  unsigned hw[4], lw[4];
#pragma unroll
  for (int p = 0; p < 4; p++) {
    unsigned u0 = ua[2 * p], u1 = ua[2 * p + 1];
    unsigned h0 = u0 & 0xFFFF0000u, h1 = u1 & 0xFFFF0000u;
    float l0 = __uint_as_float(u0) - __uint_as_float(h0);
    float l1 = __uint_as_float(u1) - __uint_as_float(h1);
    hw[p] = (u0 >> 16) | h1;
    lw[p] = (__float_as_uint(l0) >> 16) | (__float_as_uint(l1) & 0xFFFF0000u);
  }
  xh = make_uint4(hw[0], hw[1], hw[2], hw[3]);
  xl = make_uint4(lw[0], lw[1], lw[2], lw[3]);
}

// --- gemm1: Cbf16[M][64] = x[M][256] @ W1, 64 n/w, W table in LDS -----------
// Block = 256 nodes (4 waves x 64).  The 64 KB split-W table is cooperatively
// loaded into LDS ONCE per block (XOR-swizzled: chunk k ^= row&7, else all 16
// lanes of a fragment read hit bank 0 at the 512 B row stride) -- per-iter
// weight traffic becomes LDS-only (was 64 KB/wave from L2 = 100 MB chip-wide).
// x staged via global_load_lds into a 2-buffer ring (64 KB).  LDS = 128 KB ->
// 1 block/CU; per-wave DMA depth 16 KB covers the HBM latency-BW product.
// Ledger (only x in VM queue): entering iter j = [st(j):8, st(j+1):8 (j<7)]
// -> vmcnt(8) drains st(j) (j=7: vmcnt(0)).  lgkmcnt(0) before re-staging
// buf j&1 guards the 2-buf read/overwrite race.  One barrier total (W load).
__global__ __launch_bounds__(256, 1) void gemm1_mfma(const float* __restrict__ A,
                                                     const ushort_t* __restrict__ Wt,
                                                     uint2* __restrict__ Cb, int M) {
  constexpr int K = 256;
  __shared__ uint4 xtile[2][4][512];  // [ring buf][wave][slot] = 64 KB
  __shared__ uint4 wlds[4096];        // 64 KB: idx = p*2048 + row*32 + (k^(row&7))
  const int lane = threadIdx.x & 63;
  const int wv = threadIdx.x >> 6;
  const int l15 = lane & 15;
  const int lq = lane >> 4;
  const int m0 = blockIdx.x * 256 + wv * 64;

  // cooperative swizzled W load (4096 uint4, 16 per thread)
  {
    const uint4* wg = (const uint4*)Wt;  // global: idx = p*2048 + row*32 + k
    for (int i = threadIdx.x; i < 4096; i += 256) {
      int row = (i >> 5) & 63;
      int k = i & 31;
      wlds[(i & ~31) | (k ^ (row & 7))] = wg[i];
    }
  }
  __syncthreads();  // drains all counters -> clean ledger

  f32x4 acc[4][4];  // [mt][nt] = 64 VGPRs
#pragma unroll
  for (int a = 0; a < 4; a++)
#pragma unroll
    for (int b = 0; b < 4; b++) acc[a][b] = (f32x4){0.f, 0.f, 0.f, 0.f};

  // stage tile kt into ring buffer buf (this wave's 64 rows, 8 KB, 8 calls)
  auto stage_tile = [&](int kt, int buf) {
#pragma unroll
    for (int c = 0; c < 8; c++) {
      int s = c * 64 + lane;           // 0..511
      int r = s >> 3;                  // row 0..63 within wave block
      int c4 = (s & 7) ^ (r & 7);      // swizzled float4-column
      int nd = m0 + r;
      if (nd >= M) nd = M - 1;
      const float* gp = A + (size_t)nd * K + kt * 32 + c4 * 4;
      __builtin_amdgcn_global_load_lds(
          (const __attribute__((address_space(1))) void*)gp,
          (__attribute__((address_space(3))) void*)&xtile[buf][wv][c * 64], 16, 0, 0);
    }
  };

  // prologue: st(0), st(1)
  stage_tile(0, 0);
  stage_tile(1, 1);
  __builtin_amdgcn_sched_barrier(0);

#pragma unroll
  for (int j = 0; j < 8; j++) {
    // a. weight fragments from LDS (swizzled)
    FragB w[8];
#pragma unroll
    for (int nt = 0; nt < 4; nt++) {
      int row = nt * 16 + l15;
      int kc = (j * 4 + lq) ^ (row & 7);
      w[nt].u = wlds[row * 32 + kc];
      w[4 + nt].u = wlds[2048 + row * 32 + kc];
    }
    __builtin_amdgcn_sched_barrier(0);
    // b. ensure tile j staged: VM queue=[st(j):8, st(j+1):8 (j<7)]
    if (j < 7)
      asm volatile("s_waitcnt vmcnt(8)" ::: "memory");
    else
      asm volatile("s_waitcnt vmcnt(0)" ::: "memory");
    __builtin_amdgcn_sched_barrier(0);
    // c. ds_read tile j fragments (swizzled), 4 m-tiles x 2 halves
    uint4 xa[4][2];
#pragma unroll
    for (int mt = 0; mt < 4; mt++) {
      int mr = mt * 16 + l15;
#pragma unroll
      for (int hh = 0; hh < 2; hh++) {
        int c4 = (lq * 2 + hh) ^ (mr & 7);
        xa[mt][hh] = *(const uint4*)&xtile[j & 1][wv][mr * 8 + c4];
      }
    }
    __builtin_amdgcn_sched_barrier(0);
    // d. reads must COMPLETE before re-staging this buffer (2-buf race guard)
    asm volatile("s_waitcnt lgkmcnt(0)" ::: "memory");
    __builtin_amdgcn_sched_barrier(0);
    if (j + 2 < 8) stage_tile(j + 2, j & 1);
    __builtin_amdgcn_sched_barrier(0);
    // e. per m-tile: split + 12 MFMA
#pragma unroll
    for (int mt = 0; mt < 4; mt++) {
      FragB xh, xl;
      split8u(xa[mt][0], xa[mt][1], xh.u, xl.u);
#pragma unroll
      for (int nt = 0; nt < 4; nt++) {
        acc[mt][nt] = __builtin_amdgcn_mfma_f32_16x16x32_bf16(w[nt].b, xh.b, acc[mt][nt], 0, 0, 0);
        acc[mt][nt] = __builtin_amdgcn_mfma_f32_16x16x32_bf16(w[nt].b, xl.b, acc[mt][nt], 0, 0, 0);
      }
#pragma unroll
      for (int nt = 0; nt < 4; nt++) {
        acc[mt][nt] =
            __builtin_amdgcn_mfma_f32_16x16x32_bf16(w[4 + nt].b, xh.b, acc[mt][nt], 0, 0, 0);
      }
    }
  }

#pragma unroll
  for (int mt = 0; mt < 4; mt++) {
    int node = m0 + mt * 16 + l15;
    if (node < M) {
      uint2* cp = Cb + (size_t)node * 16 + lq;
#pragma unroll
      for (int nt = 0; nt < 4; nt++) {
        float4 o = make_float4(acc[mt][nt][0], acc[mt][nt][1], acc[mt][nt][2], acc[mt][nt][3]);
        cp[nt * 4] = f42bfq(o);  // cols nt*16 + lq*4 .. +3
      }
    }
  }
}

// --- gemm2: Cbf16[M][64] = out1[M][64] @ W2 (32 n/w, W2 in LDS 16 KB) -------
// Same LDS-W trick: kills the 16 KB/wave L2 re-stream (was 50 MB chip-wide).
// Swizzle: K=64 -> 8 chunks/row; chunk k ^= row&7 spreads the 16-lane
// stride-128B fragment reads across all banks.
__global__ __launch_bounds__(256, 3) void gemm2_mfma(const ushort_t* __restrict__ Av,
                                                     const ushort_t* __restrict__ Wt,
                                                     uint2* __restrict__ Cb, int M) {
  constexpr int K = 64;
  constexpr int NT = K / 32;  // 2
  __shared__ uint4 w2[1024];  // 16 KB: idx = p*512 + row*8 + (k^(row&7))
  const int lane = threadIdx.x & 63;
  const int wv = threadIdx.x >> 6;
  const int l15 = lane & 15;
  const int lq = lane >> 4;
  const int m0 = blockIdx.x * 128 + wv * 32;

  {
    const uint4* wg = (const uint4*)Wt;  // global: idx = p*512 + row*8 + k
    for (int i = threadIdx.x; i < 1024; i += 256) {
      int row = (i >> 3) & 63;
      int k = i & 7;
      w2[(i & ~7) | (k ^ (row & 7))] = wg[i];
    }
  }
  __syncthreads();

  f32x4 acc[2][4];
#pragma unroll
  for (int a = 0; a < 2; a++)
#pragma unroll
    for (int b = 0; b < 4; b++) acc[a][b] = (f32x4){0.f, 0.f, 0.f, 0.f};

  int node[2], ncl[2];
#pragma unroll
  for (int mt = 0; mt < 2; mt++) {
    node[mt] = m0 + mt * 16 + l15;
    ncl[mt] = node[mt] < M ? node[mt] : (M - 1);
  }

  FragB xa[NT][2];
#pragma unroll
  for (int t = 0; t < NT; t++)
#pragma unroll
    for (int mt = 0; mt < 2; mt++)
      xa[t][mt].u = *(const uint4*)(Av + (size_t)ncl[mt] * K + t * 32 + lq * 8);

#pragma unroll
  for (int t = 0; t < NT; t++) {
    FragB wh[4], wl[4];
#pragma unroll
    for (int nt = 0; nt < 4; nt++) {
      int row = nt * 16 + l15;
      int kc = (t * 4 + lq) ^ (row & 7);
      wh[nt].u = w2[row * 8 + kc];
      wl[nt].u = w2[512 + row * 8 + kc];
    }
#pragma unroll
    for (int mt = 0; mt < 2; mt++)
#pragma unroll
      for (int nt = 0; nt < 4; nt++) {
        acc[mt][nt] =
            __builtin_amdgcn_mfma_f32_16x16x32_bf16(wh[nt].b, xa[t][mt].b, acc[mt][nt], 0, 0, 0);
        acc[mt][nt] =
            __builtin_amdgcn_mfma_f32_16x16x32_bf16(wl[nt].b, xa[t][mt].b, acc[mt][nt], 0, 0, 0);
      }
  }

#pragma unroll
  for (int mt = 0; mt < 2; mt++) {
    if (node[mt] < M) {
      uint2* cp = Cb + (size_t)node[mt] * 16 + lq;
#pragma unroll
      for (int nt = 0; nt < 4; nt++) {
        float4 o = make_float4(acc[mt][nt][0], acc[mt][nt][1], acc[mt][nt][2], acc[mt][nt][3]);
        cp[nt * 4] = f42bfq(o);
      }
    }
  }
}

// --- aggregation: wave per node, depth-4 rolling gather pipeline ------------
// Fabric-roofline-bound (~165 MB L2-miss @ ~2.8 TB/s); structure kept.
template <bool OUTBF>
__global__ __launch_bounds__(256) void agg_kernel(
    const uint2* __restrict__ h, const int* __restrict__ rowptr, const int* __restrict__ col,
    const float* __restrict__ dis, const float* __restrict__ bias, void* __restrict__ outv,
    int N, int relu) {
  int wid = (blockIdx.x * blockDim.x + threadIdx.x) >> 6;
  if (wid >= N) return;
  int lane = threadIdx.x & 63;
  int sub = lane & 15;
  int quarter = lane >> 4;

  int start = rowptr[wid], end = rowptr[wid + 1];
  float di = dis[wid];

  float4 a0 = make_float4(0.f, 0.f, 0.f, 0.f), a1 = a0, a2 = a0, a3 = a0;
  {  // self-loop: di*h_self (quarter 0 only); final *di makes it di^2
    float4 self = bfq2f4(h[(size_t)wid * 16 + sub]);
    if (quarter == 0) {
      a0.x = di * self.x;
      a0.y = di * self.y;
      a0.z = di * self.z;
      a0.w = di * self.w;
    }
  }

  for (int base = start; base < end; base += 64) {
    int e = base + lane;
    int sj = 0;
    float wj = 0.f;
    if (e < end) {
      sj = col[e];
      wj = dis[sj];  // L2-resident 400 KB table
    }
    int cnt = end - base;
    if (cnt > 64) cnt = 64;
    int rounds = (cnt + 3) >> 2;  // wave-uniform

    uint2 g0, g1, g2, g3;
    float w0, w1, w2, w3;
#define ISSUE(gi, G, W)                                              \
  do {                                                               \
    int _i = (4 * (gi) + quarter) & 63;                              \
    int _s = __shfl(sj, _i);                                         \
    float _w = __shfl(wj, _i);                                       \
    if ((gi) < rounds) {                                             \
      G = h[(size_t)_s * 16 + sub];                                  \
      W = _w;                                                        \
    } else {                                                         \
      G = make_uint2(0u, 0u);                                        \
      W = 0.f;                                                       \
    }                                                                \
  } while (0)

    ISSUE(0, g0, w0);
    ISSUE(1, g1, w1);
    ISSUE(2, g2, w2);
    ISSUE(3, g3, w3);
    int rounds4 = (rounds + 3) & ~3;
    for (int t0 = 0; t0 < rounds4; t0 += 4) {
      {
        float4 gf = bfq2f4(g0);
        a0.x += w0 * gf.x; a0.y += w0 * gf.y; a0.z += w0 * gf.z; a0.w += w0 * gf.w;
      }
      ISSUE(t0 + 4, g0, w0);
      {
        float4 gf = bfq2f4(g1);
        a1.x += w1 * gf.x; a1.y += w1 * gf.y; a1.z += w1 * gf.z; a1.w += w1 * gf.w;
      }
      ISSUE(t0 + 5, g1, w1);
      {
        float4 gf = bfq2f4(g2);
        a2.x += w2 * gf.x; a2.y += w2 * gf.y; a2.z += w2 * gf.z; a2.w += w2 * gf.w;
      }
      ISSUE(t0 + 6, g2, w2);
      {
        float4 gf = bfq2f4(g3);
        a3.x += w3 * gf.x; a3.y += w3 * gf.y; a3.z += w3 * gf.z; a3.w += w3 * gf.w;
      }
      ISSUE(t0 + 7, g3, w3);
    }
#undef ISSUE
  }

  float sx = (a0.x + a1.x) + (a2.x + a3.x);
  float sy = (a0.y + a1.y) + (a2.y + a3.y);
  float sz = (a0.z + a1.z) + (a2.z + a3.z);
  float sw = (a0.w + a1.w) + (a2.w + a3.w);
  sx += __shfl_down(sx, 32); sy += __shfl_down(sy, 32);
  sz += __shfl_down(sz, 32); sw += __shfl_down(sw, 32);
  sx += __shfl_down(sx, 16); sy += __shfl_down(sy, 16);
  sz += __shfl_down(sz, 16); sw += __shfl_down(sw, 16);
  if (quarter == 0) {
    float4 bv = ((const float4*)bias)[sub];
    float4 o = make_float4(di * sx + bv.x, di * sy + bv.y, di * sz + bv.z, di * sw + bv.w);
    if (relu) {
      o.x = fmaxf(o.x, 0.f);
      o.y = fmaxf(o.y, 0.f);
      o.z = fmaxf(o.z, 0.f);
      o.w = fmaxf(o.w, 0.f);
    }
    if (OUTBF)
      ((uint2*)outv)[(size_t)wid * 16 + sub] = f42bfq(o);
    else
      ((float4*)outv)[(size_t)wid * 16 + sub] = o;
  }
}

// ---------------------------------------------------------------------------
extern "C" void kernel_launch(void* const* d_in, const int* in_sizes, int n_in,
                              void* d_out, int out_size, void* d_ws, size_t ws_size,
                              hipStream_t stream) {
  const float* x = (const float*)d_in[0];
  const int* ei = (const int*)d_in[1];
  const float* W1 = (const float*)d_in[2];
  const float* b1 = (const float*)d_in[3];
  const float* W2 = (const float*)d_in[4];
  const float* b2 = (const float*)d_in[5];

  const int IN = 256;
  const int E = in_sizes[1] / 2;
  const int N = in_sizes[0] / IN;
  const int* src = ei;
  const int* dst = ei + E;
  const int nbins = (N + BIN_NODES - 1) >> BIN_SHIFT;
  const int nsup = (N + (1 << SUP_SHIFT) - 1) >> SUP_SHIFT;

  // workspace carve-up (256B aligned)
  char* ws = (char*)d_ws;
  size_t off = 0;
  auto alloc = [&](size_t bytes) -> void* {
    void* p = ws + off;
    off += (bytes + 255) & ~(size_t)255;
    return p;
  };
  int* rowptr = (int*)alloc((size_t)(N + 1) * 4);
  float* dis = (float*)alloc((size_t)N * 4);
  int* binCnt = (int*)alloc(MAX_BINS * 4);
  int* binStart = (int*)alloc((MAX_BINS + 1) * 4);
  int* binCursor = (int*)alloc(MAX_BINS * 4);
  int* supCursor = (int*)alloc(NSUP_MAX * 4);
  int* col = (int*)alloc((size_t)E * 4);                // 12.8 MB; written by bin_csr
  unsigned* supbuf = (unsigned*)col;                    // alias: dead before col written
  uint2* out1 = (uint2*)alloc((size_t)N * 64 * 2);      // bf16 layer-1 activations
  size_t big = ((size_t)E * 4 > (size_t)N * 128) ? (size_t)E * 4 : (size_t)N * 128;
  unsigned* binbuf = (unsigned*)alloc(big);             // aliases h (dead before gemm1)
  uint2* h = (uint2*)binbuf;
  ushort_t* wt1 = (ushort_t*)alloc((size_t)2 * 64 * 256 * 2);  // 64 KB split W1
  ushort_t* wt2 = (ushort_t*)alloc((size_t)2 * 64 * 64 * 2);   // 16 KB split W2
  float* outf = (float*)d_out;

  prep<<<(256 * 64 + 64 * 64 + 255) / 256, 256, 0, stream>>>(W1, W2, wt1, wt2, binCnt, nbins);
  bin_count<<<1024, 256, 0, stream>>>(dst, E, nbins, binCnt);
  bin_scan<<<1, 256, 0, stream>>>(binCnt, nbins, E, binStart, binCursor, supCursor);
  super_fill<<<(E + 2047) / 2048, 256, 0, stream>>>(src, dst, E, nsup, supCursor, supbuf);
  fine_fill<<<nsup * 8, 256, 0, stream>>>(supbuf, binStart, nbins, binCursor, binbuf);
  bin_csr<<<nbins, 256, 0, stream>>>(binbuf, binStart, N, E, rowptr, col, dis);

  gemm1_mfma<<<(N + 255) / 256, 256, 0, stream>>>(x, wt1, h, N);
  agg_kernel<true><<<(N + 3) / 4, 256, 0, stream>>>(h, rowptr, col, dis, b1, out1, N, 1);
  gemm2_mfma<<<(N + 127) / 128, 256, 0, stream>>>((const ushort_t*)out1, wt2, h, N);
  agg_kernel<false><<<(N + 3) / 4, 256, 0, stream>>>(h, rowptr, col, dis, b2, outf, N, 0);
}

// Round 13
// 443.625 us; speedup vs baseline: 1.0758x; 1.0086x over previous
//
#include <hip/hip_runtime.h>
#include <cstdint>
#include <cstddef>

// ---------------------------------------------------------------------------
// GCN 2-layer encoder.  Pipeline per launch (10 dispatches):
//   1. prep: zero binCnt + count + wsplit (W1/W2 -> split-bf16 hi/lo planes)
//   2. bin_count: 782-bin histogram of dst>>7
//   3. bin_scan:  binStart/binCursor (fine) + superCursor (dst>>11, 49 bins)
//   4. super_fill: partition edges into super-bins (1 tile/block)
//   5. fine_fill: scatter super-segment into 16 fine bins, 32 partitions per
//      super (6 blocks/CU TLP) + FUSED per-node degree count -> count[]
//   6. bin_csr: dis + scan + CSR col scatter (count pass eliminated -- reads
//      count[]; one binbuf pass instead of two)
//   7. gemm1_mfma -> h1 bf16 (64 n/w, W table in LDS, x LDS-DMA ring)
//   8. agg1 -> out1 (bf16, relu)  [fabric-roofline ~2.8 TB/s, left as-is]
//   9. gemm2_mfma -> h2 bf16 (32 n/w, W2 in LDS 16 KB, A exact bf16)
//  10. agg2 -> d_out (fp32)
// MFMA orientation: D[n][m] = Wt[n][k] * x[m][k]^T so each lane holds 4
// consecutive output cols of one node -> packs straight into uint2 bf16.
// ---------------------------------------------------------------------------

#define BIN_SHIFT 7
#define BIN_NODES 128
#define MAX_BINS 1024
#define SUP_SHIFT 11
#define SUP_NODES 2048
#define FINE_PER_SUP 16
#define NSUP_MAX 64
#define SCAP 56  // per-super staging capacity per 2048-edge tile (mean 42)
#define PARTS 32 // fine_fill partitions per super-bin
#define SRC_BITS 17
#define SRC_MASK ((1 << SRC_BITS) - 1)

typedef unsigned short ushort_t;

typedef __attribute__((ext_vector_type(8))) short bf16x8;  // 8 bf16 (4 VGPRs)
typedef __attribute__((ext_vector_type(4))) float f32x4;   // MFMA accumulator

union FragB {
  uint4 u;
  bf16x8 b;
};

__device__ __forceinline__ float4 bfq2f4(uint2 p) {  // 4 packed bf16 -> fp32 (exact)
  float4 r;
  r.x = __uint_as_float(p.x << 16);
  r.y = __uint_as_float(p.x & 0xFFFF0000u);
  r.z = __uint_as_float(p.y << 16);
  r.w = __uint_as_float(p.y & 0xFFFF0000u);
  return r;
}
__device__ __forceinline__ unsigned f2bf(float f) {  // fp32 -> bf16 bits, RNE
  unsigned u = __float_as_uint(f);
  return (u + 0x7FFFu + ((u >> 16) & 1u)) >> 16;
}
__device__ __forceinline__ uint2 f42bfq(float4 f) {
  uint2 r;
  r.x = f2bf(f.x) | (f2bf(f.y) << 16);
  r.y = f2bf(f.z) | (f2bf(f.w) << 16);
  return r;
}

// --- pass 1: prep = zero binCnt/count + wsplit ------------------------------
// wt layout: [plane(hi=0,lo=1)][n(64)][k(K)] bf16.  hi = truncation,
// lo = bf16_trunc(w - hi_as_f32); hi+lo represents w to ~2^-16 relative.
__global__ __launch_bounds__(256) void prep(const float* __restrict__ W1,
                                            const float* __restrict__ W2,
                                            ushort_t* __restrict__ wt1,
                                            ushort_t* __restrict__ wt2,
                                            int* __restrict__ binCnt, int nbins,
                                            int* __restrict__ count, int N) {
  int i = blockIdx.x * 256 + threadIdx.x;
  if (i < nbins) binCnt[i] = 0;
  if (i < N) count[i] = 0;
  const float* W;
  ushort_t* wt;
  int K, idx;
  if (i < 256 * 64) {
    W = W1; wt = wt1; K = 256; idx = i;
  } else if (i < 256 * 64 + 64 * 64) {
    W = W2; wt = wt2; K = 64; idx = i - 256 * 64;
  } else
    return;
  int n = idx & 63, k = idx >> 6;
  float f = W[k * 64 + n];  // W is [K][64] row-major
  unsigned u = __float_as_uint(f);
  unsigned hb = u & 0xFFFF0000u;
  float lo = f - __uint_as_float(hb);
  wt[(size_t)n * K + k] = (ushort_t)(u >> 16);
  wt[(size_t)64 * K + (size_t)n * K + k] = (ushort_t)(__float_as_uint(lo) >> 16);
}

// --- pass 2: fine histogram -------------------------------------------------
__global__ __launch_bounds__(256) void bin_count(const int* __restrict__ dst, int E, int nbins,
                                                 int* __restrict__ binCnt) {
  __shared__ int h[MAX_BINS];
  for (int i = threadIdx.x; i < nbins; i += 256) h[i] = 0;
  __syncthreads();
  int stride = gridDim.x * 256;
  for (int e = blockIdx.x * 256 + threadIdx.x; e < E; e += stride)
    atomicAdd(&h[dst[e] >> BIN_SHIFT], 1);
  __syncthreads();
  for (int i = threadIdx.x; i < nbins; i += 256)
    if (h[i]) atomicAdd(&binCnt[i], h[i]);
}

// --- pass 3: scan fine bins; derive super cursors ---------------------------
__global__ __launch_bounds__(256) void bin_scan(const int* __restrict__ binCnt, int nbins, int E,
                                                int* __restrict__ binStart,
                                                int* __restrict__ binCursor,
                                                int* __restrict__ supCursor) {
  __shared__ int s[256];
  int t = threadIdx.x;
  int c[4];
  int sum = 0;
#pragma unroll
  for (int i = 0; i < 4; i++) {
    int idx = t * 4 + i;
    c[i] = (idx < nbins) ? binCnt[idx] : 0;
    sum += c[i];
  }
  int v = sum;
  s[t] = v;
  __syncthreads();
  for (int d = 1; d < 256; d <<= 1) {
    int add = (t >= d) ? s[t - d] : 0;
    __syncthreads();
    s[t] += add;
    __syncthreads();
  }
  int run = s[t] - v;  // exclusive prefix
#pragma unroll
  for (int i = 0; i < 4; i++) {
    int idx = t * 4 + i;
    if (idx < nbins) {
      binStart[idx] = run;
      binCursor[idx] = run;
      if ((idx & (FINE_PER_SUP - 1)) == 0) supCursor[idx >> 4] = run;  // super segment start
      run += c[i];
    }
  }
  if (t == 0) binStart[nbins] = E;
}

// --- pass 4: partition into super-bins, one 2048-edge tile per block --------
__global__ __launch_bounds__(256) void super_fill(const int* __restrict__ src,
                                                  const int* __restrict__ dst, int E, int nsup,
                                                  int* __restrict__ supCursor,
                                                  unsigned* __restrict__ supbuf) {
  __shared__ unsigned stage[NSUP_MAX * SCAP];
  __shared__ int lcnt[NSUP_MAX], lbase[NSUP_MAX], lscan[NSUP_MAX + 1];
  const int tid = threadIdx.x;
  const int t0 = blockIdx.x * 2048;
  const int t1 = min(E, t0 + 2048);

  int dv[8], sv[8];
#pragma unroll
  for (int i = 0; i < 8; i++) {
    int e = t0 + i * 256 + tid;
    if (e < t1) {
      dv[i] = dst[e];
      sv[i] = src[e];
    }
  }
  if (tid < nsup) lcnt[tid] = 0;
  __syncthreads();
#pragma unroll
  for (int i = 0; i < 8; i++) {
    int e = t0 + i * 256 + tid;
    if (e < t1) {
      int d = dv[i];
      int sb = d >> SUP_SHIFT;
      unsigned v = ((unsigned)(d & ((1 << SUP_SHIFT) - 1)) << SRC_BITS) | (unsigned)sv[i];
      int idx = atomicAdd(&lcnt[sb], 1);
      if (idx < SCAP)
        stage[sb * SCAP + idx] = v;
      else {  // rare overflow: direct write
        int g = atomicAdd(&supCursor[sb], 1);
        supbuf[g] = v;
      }
    }
  }
  __syncthreads();
  if (tid < nsup) {
    int c = min(lcnt[tid], SCAP);
    lcnt[tid] = c;
    lbase[tid] = c ? atomicAdd(&supCursor[tid], c) : 0;
  }
  __syncthreads();
  if (tid < 64) {  // wave-0 inclusive scan over 64 bins
    int vv = (tid < nsup) ? lcnt[tid] : 0;
    int ss = vv;
#pragma unroll
    for (int d = 1; d < 64; d <<= 1) {
      int u = __shfl_up(ss, d);
      if (tid >= d) ss += u;
    }
    lscan[tid + 1] = ss;
    if (tid == 0) lscan[0] = 0;
  }
  __syncthreads();
  int total = lscan[nsup];
  for (int j = tid; j < total; j += 256) {
    int lo = 0, hi = nsup;  // binary search: lscan[lo] <= j < lscan[lo+1]
    while (hi - lo > 1) {
      int mid = (lo + hi) >> 1;
      if (lscan[mid] <= j)
        lo = mid;
      else
        hi = mid;
    }
    int off = j - lscan[lo];
    supbuf[lbase[lo] + off] = stage[lo * SCAP + off];
  }
}

// --- pass 5: fine scatter (32 parts/super) + FUSED per-node degree count ----
__global__ __launch_bounds__(256) void fine_fill(const unsigned* __restrict__ supbuf,
                                                 const int* __restrict__ binStart, int nbins,
                                                 int* __restrict__ binCursor,
                                                 unsigned* __restrict__ binbuf,
                                                 int* __restrict__ count, int N) {
  __shared__ int cnt[SUP_NODES];  // 8 KB per-node degree (dst-local to super)
  __shared__ int lcnt[FINE_PER_SUP], lbase[FINE_PER_SUP];
  int sb = blockIdx.x / PARTS, p = blockIdx.x % PARTS;
  int seg0 = binStart[sb << 4];
  int seg1 = binStart[min((sb + 1) << 4, nbins)];
  int part = (seg1 - seg0 + PARTS - 1) / PARTS;
  int c0 = seg0 + p * part;
  int c1 = min(seg1, c0 + part);
  for (int i = threadIdx.x; i < SUP_NODES; i += 256) cnt[i] = 0;
  if (threadIdx.x < FINE_PER_SUP) lcnt[threadIdx.x] = 0;
  __syncthreads();
  for (int i = c0 + threadIdx.x; i < c1; i += 256) {
    unsigned v = supbuf[i];
    atomicAdd(&lcnt[v >> (SRC_BITS + BIN_SHIFT)], 1);
    atomicAdd(&cnt[v >> SRC_BITS], 1);
  }
  __syncthreads();
  if (threadIdx.x < FINE_PER_SUP) {
    int c = lcnt[threadIdx.x];
    lbase[threadIdx.x] = c ? atomicAdd(&binCursor[(sb << 4) + threadIdx.x], c) : 0;
    lcnt[threadIdx.x] = 0;
  }
  // flush per-node counts (L2-resident 400 KB count[] table)
  int nodeBase = sb << SUP_SHIFT;
  for (int i = threadIdx.x; i < SUP_NODES; i += 256) {
    int c = cnt[i];
    int node = nodeBase + i;
    if (c && node < N) atomicAdd(&count[node], c);
  }
  __syncthreads();
  for (int i = c0 + threadIdx.x; i < c1; i += 256) {
    unsigned v = supbuf[i];
    unsigned dls = v >> SRC_BITS;  // 11-bit dst-local-to-super
    int f = dls >> BIN_SHIFT;      // fine bin within super
    unsigned vf = ((dls & (BIN_NODES - 1)) << SRC_BITS) | (v & SRC_MASK);
    int idx = lbase[f] + atomicAdd(&lcnt[f], 1);
    binbuf[idx] = vf;
  }
}

// --- pass 6: dis + scan + CSR col scatter (count[] precomputed) -------------
__global__ __launch_bounds__(256) void bin_csr(const unsigned* __restrict__ binbuf,
                                               const int* __restrict__ binStart,
                                               const int* __restrict__ count, int N, int E,
                                               int* __restrict__ rowptr, int* __restrict__ col,
                                               float* __restrict__ dis) {
  __shared__ int cur[BIN_NODES];
  __shared__ int pref[BIN_NODES];
  int b = blockIdx.x, t = threadIdx.x;
  int nodeBase = b << BIN_SHIFT;
  int c = 0;
  if (t < BIN_NODES) {
    int node = nodeBase + t;
    if (node < N) {
      c = count[node];
      dis[node] = rsqrtf((float)(c + 1));  // +1 self loop
    }
    pref[t] = c;
  }
  __syncthreads();
  for (int d = 1; d < BIN_NODES; d <<= 1) {  // inclusive scan over 128
    int add = (t < BIN_NODES && t >= d) ? pref[t - d] : 0;
    __syncthreads();
    if (t < BIN_NODES) pref[t] += add;
    __syncthreads();
  }
  int s0 = binStart[b];
  if (t < BIN_NODES) {
    int node = nodeBase + t;
    if (node < N) {
      int ex = s0 + pref[t] - c;  // exclusive prefix + segment base
      rowptr[node] = ex;
      cur[t] = ex;
    }
  }
  if (b == 0 && t == 255) rowptr[N] = E;
  __syncthreads();
  int s1 = binStart[b + 1];
  for (int i = s0 + t; i < s1; i += 256) {
    unsigned v = binbuf[i];
    int slot = atomicAdd(&cur[v >> SRC_BITS], 1);
    col[slot] = v & SRC_MASK;
  }
}

// split 8 packed fp32 (as 2 uint4) into bf16 hi (truncate) + lo (trunc resid)
__device__ __forceinline__ void split8u(uint4 a, uint4 b, uint4& xh, uint4& xl) {
  unsigned ua[8] = {a.x, a.y, a.z, a.w, b.x, b.y, b.z, b.w};
  unsigned hw[4], lw[4];
#pragma unroll
  for (int p = 0; p < 4; p++) {
    unsigned u0 = ua[2 * p], u1 = ua[2 * p + 1];
    unsigned h0 = u0 & 0xFFFF0000u, h1 = u1 & 0xFFFF0000u;
    float l0 = __uint_as_float(u0) - __uint_as_float(h0);
    float l1 = __uint_as_float(u1) - __uint_as_float(h1);
    hw[p] = (u0 >> 16) | h1;
    lw[p] = (__float_as_uint(l0) >> 16) | (__float_as_uint(l1) & 0xFFFF0000u);
  }
  xh = make_uint4(hw[0], hw[1], hw[2], hw[3]);
  xl = make_uint4(lw[0], lw[1], lw[2], lw[3]);
}

// --- gemm1: Cbf16[M][64] = x[M][256] @ W1, 64 n/w, W table in LDS -----------
// Block = 256 nodes (4 waves x 64).  64 KB split-W cooperatively loaded into
// LDS once (XOR-swizzled), per-iter weight traffic LDS-only.  x staged via
// global_load_lds into a 2-buffer ring (64 KB).  128 KB LDS -> 1 block/CU.
// Ledger (only x in VM queue): entering iter j = [st(j):8, st(j+1):8 (j<7)]
// -> vmcnt(8)/(0).  lgkmcnt(0) guards the 2-buf read/overwrite race.
__global__ __launch_bounds__(256, 1) void gemm1_mfma(const float* __restrict__ A,
                                                     const ushort_t* __restrict__ Wt,
                                                     uint2* __restrict__ Cb, int M) {
  constexpr int K = 256;
  __shared__ uint4 xtile[2][4][512];  // [ring buf][wave][slot] = 64 KB
  __shared__ uint4 wlds[4096];        // 64 KB: idx = p*2048 + row*32 + (k^(row&7))
  const int lane = threadIdx.x & 63;
  const int wv = threadIdx.x >> 6;
  const int l15 = lane & 15;
  const int lq = lane >> 4;
  const int m0 = blockIdx.x * 256 + wv * 64;

  // cooperative swizzled W load (4096 uint4, 16 per thread)
  {
    const uint4* wg = (const uint4*)Wt;  // global: idx = p*2048 + row*32 + k
    for (int i = threadIdx.x; i < 4096; i += 256) {
      int row = (i >> 5) & 63;
      int k = i & 31;
      wlds[(i & ~31) | (k ^ (row & 7))] = wg[i];
    }
  }
  __syncthreads();  // drains all counters -> clean ledger

  f32x4 acc[4][4];  // [mt][nt] = 64 VGPRs
#pragma unroll
  for (int a = 0; a < 4; a++)
#pragma unroll
    for (int b = 0; b < 4; b++) acc[a][b] = (f32x4){0.f, 0.f, 0.f, 0.f};

  // stage tile kt into ring buffer buf (this wave's 64 rows, 8 KB, 8 calls)
  auto stage_tile = [&](int kt, int buf) {
#pragma unroll
    for (int c = 0; c < 8; c++) {
      int s = c * 64 + lane;           // 0..511
      int r = s >> 3;                  // row 0..63 within wave block
      int c4 = (s & 7) ^ (r & 7);      // swizzled float4-column
      int nd = m0 + r;
      if (nd >= M) nd = M - 1;
      const float* gp = A + (size_t)nd * K + kt * 32 + c4 * 4;
      __builtin_amdgcn_global_load_lds(
          (const __attribute__((address_space(1))) void*)gp,
          (__attribute__((address_space(3))) void*)&xtile[buf][wv][c * 64], 16, 0, 0);
    }
  };

  // prologue: st(0), st(1)
  stage_tile(0, 0);
  stage_tile(1, 1);
  __builtin_amdgcn_sched_barrier(0);

#pragma unroll
  for (int j = 0; j < 8; j++) {
    // a. weight fragments from LDS (swizzled)
    FragB w[8];
#pragma unroll
    for (int nt = 0; nt < 4; nt++) {
      int row = nt * 16 + l15;
      int kc = (j * 4 + lq) ^ (row & 7);
      w[nt].u = wlds[row * 32 + kc];
      w[4 + nt].u = wlds[2048 + row * 32 + kc];
    }
    __builtin_amdgcn_sched_barrier(0);
    // b. ensure tile j staged: VM queue=[st(j):8, st(j+1):8 (j<7)]
    if (j < 7)
      asm volatile("s_waitcnt vmcnt(8)" ::: "memory");
    else
      asm volatile("s_waitcnt vmcnt(0)" ::: "memory");
    __builtin_amdgcn_sched_barrier(0);
    // c. ds_read tile j fragments (swizzled), 4 m-tiles x 2 halves
    uint4 xa[4][2];
#pragma unroll
    for (int mt = 0; mt < 4; mt++) {
      int mr = mt * 16 + l15;
#pragma unroll
      for (int hh = 0; hh < 2; hh++) {
        int c4 = (lq * 2 + hh) ^ (mr & 7);
        xa[mt][hh] = *(const uint4*)&xtile[j & 1][wv][mr * 8 + c4];
      }
    }
    __builtin_amdgcn_sched_barrier(0);
    // d. reads must COMPLETE before re-staging this buffer (2-buf race guard)
    asm volatile("s_waitcnt lgkmcnt(0)" ::: "memory");
    __builtin_amdgcn_sched_barrier(0);
    if (j + 2 < 8) stage_tile(j + 2, j & 1);
    __builtin_amdgcn_sched_barrier(0);
    // e. per m-tile: split + 12 MFMA
#pragma unroll
    for (int mt = 0; mt < 4; mt++) {
      FragB xh, xl;
      split8u(xa[mt][0], xa[mt][1], xh.u, xl.u);
#pragma unroll
      for (int nt = 0; nt < 4; nt++) {
        acc[mt][nt] = __builtin_amdgcn_mfma_f32_16x16x32_bf16(w[nt].b, xh.b, acc[mt][nt], 0, 0, 0);
        acc[mt][nt] = __builtin_amdgcn_mfma_f32_16x16x32_bf16(w[nt].b, xl.b, acc[mt][nt], 0, 0, 0);
      }
#pragma unroll
      for (int nt = 0; nt < 4; nt++) {
        acc[mt][nt] =
            __builtin_amdgcn_mfma_f32_16x16x32_bf16(w[4 + nt].b, xh.b, acc[mt][nt], 0, 0, 0);
      }
    }
  }

#pragma unroll
  for (int mt = 0; mt < 4; mt++) {
    int node = m0 + mt * 16 + l15;
    if (node < M) {
      uint2* cp = Cb + (size_t)node * 16 + lq;
#pragma unroll
      for (int nt = 0; nt < 4; nt++) {
        float4 o = make_float4(acc[mt][nt][0], acc[mt][nt][1], acc[mt][nt][2], acc[mt][nt][3]);
        cp[nt * 4] = f42bfq(o);  // cols nt*16 + lq*4 .. +3
      }
    }
  }
}

// --- gemm2: Cbf16[M][64] = out1[M][64] @ W2 (32 n/w, W2 in LDS 16 KB) -------
__global__ __launch_bounds__(256, 3) void gemm2_mfma(const ushort_t* __restrict__ Av,
                                                     const ushort_t* __restrict__ Wt,
                                                     uint2* __restrict__ Cb, int M) {
  constexpr int K = 64;
  constexpr int NT = K / 32;  // 2
  __shared__ uint4 w2[1024];  // 16 KB: idx = p*512 + row*8 + (k^(row&7))
  const int lane = threadIdx.x & 63;
  const int wv = threadIdx.x >> 6;
  const int l15 = lane & 15;
  const int lq = lane >> 4;
  const int m0 = blockIdx.x * 128 + wv * 32;

  {
    const uint4* wg = (const uint4*)Wt;  // global: idx = p*512 + row*8 + k
    for (int i = threadIdx.x; i < 1024; i += 256) {
      int row = (i >> 3) & 63;
      int k = i & 7;
      w2[(i & ~7) | (k ^ (row & 7))] = wg[i];
    }
  }
  __syncthreads();

  f32x4 acc[2][4];
#pragma unroll
  for (int a = 0; a < 2; a++)
#pragma unroll
    for (int b = 0; b < 4; b++) acc[a][b] = (f32x4){0.f, 0.f, 0.f, 0.f};

  int node[2], ncl[2];
#pragma unroll
  for (int mt = 0; mt < 2; mt++) {
    node[mt] = m0 + mt * 16 + l15;
    ncl[mt] = node[mt] < M ? node[mt] : (M - 1);
  }

  FragB xa[NT][2];
#pragma unroll
  for (int t = 0; t < NT; t++)
#pragma unroll
    for (int mt = 0; mt < 2; mt++)
      xa[t][mt].u = *(const uint4*)(Av + (size_t)ncl[mt] * K + t * 32 + lq * 8);

#pragma unroll
  for (int t = 0; t < NT; t++) {
    FragB wh[4], wl[4];
#pragma unroll
    for (int nt = 0; nt < 4; nt++) {
      int row = nt * 16 + l15;
      int kc = (t * 4 + lq) ^ (row & 7);
      wh[nt].u = w2[row * 8 + kc];
      wl[nt].u = w2[512 + row * 8 + kc];
    }
#pragma unroll
    for (int mt = 0; mt < 2; mt++)
#pragma unroll
      for (int nt = 0; nt < 4; nt++) {
        acc[mt][nt] =
            __builtin_amdgcn_mfma_f32_16x16x32_bf16(wh[nt].b, xa[t][mt].b, acc[mt][nt], 0, 0, 0);
        acc[mt][nt] =
            __builtin_amdgcn_mfma_f32_16x16x32_bf16(wl[nt].b, xa[t][mt].b, acc[mt][nt], 0, 0, 0);
      }
  }

#pragma unroll
  for (int mt = 0; mt < 2; mt++) {
    if (node[mt] < M) {
      uint2* cp = Cb + (size_t)node[mt] * 16 + lq;
#pragma unroll
      for (int nt = 0; nt < 4; nt++) {
        float4 o = make_float4(acc[mt][nt][0], acc[mt][nt][1], acc[mt][nt][2], acc[mt][nt][3]);
        cp[nt * 4] = f42bfq(o);
      }
    }
  }
}

// --- aggregation: wave per node, depth-4 rolling gather pipeline ------------
// Fabric-roofline-bound (~165 MB L2-miss @ ~2.8 TB/s); structure kept.
template <bool OUTBF>
__global__ __launch_bounds__(256) void agg_kernel(
    const uint2* __restrict__ h, const int* __restrict__ rowptr, const int* __restrict__ col,
    const float* __restrict__ dis, const float* __restrict__ bias, void* __restrict__ outv,
    int N, int relu) {
  int wid = (blockIdx.x * blockDim.x + threadIdx.x) >> 6;
  if (wid >= N) return;
  int lane = threadIdx.x & 63;
  int sub = lane & 15;
  int quarter = lane >> 4;

  int start = rowptr[wid], end = rowptr[wid + 1];
  float di = dis[wid];

  float4 a0 = make_float4(0.f, 0.f, 0.f, 0.f), a1 = a0, a2 = a0, a3 = a0;
  {  // self-loop: di*h_self (quarter 0 only); final *di makes it di^2
    float4 self = bfq2f4(h[(size_t)wid * 16 + sub]);
    if (quarter == 0) {
      a0.x = di * self.x;
      a0.y = di * self.y;
      a0.z = di * self.z;
      a0.w = di * self.w;
    }
  }

  for (int base = start; base < end; base += 64) {
    int e = base + lane;
    int sj = 0;
    float wj = 0.f;
    if (e < end) {
      sj = col[e];
      wj = dis[sj];  // L2-resident 400 KB table
    }
    int cnt = end - base;
    if (cnt > 64) cnt = 64;
    int rounds = (cnt + 3) >> 2;  // wave-uniform

    uint2 g0, g1, g2, g3;
    float w0, w1, w2, w3;
#define ISSUE(gi, G, W)                                              \
  do {                                                               \
    int _i = (4 * (gi) + quarter) & 63;                              \
    int _s = __shfl(sj, _i);                                         \
    float _w = __shfl(wj, _i);                                       \
    if ((gi) < rounds) {                                             \
      G = h[(size_t)_s * 16 + sub];                                  \
      W = _w;                                                        \
    } else {                                                         \
      G = make_uint2(0u, 0u);                                        \
      W = 0.f;                                                       \
    }                                                                \
  } while (0)

    ISSUE(0, g0, w0);
    ISSUE(1, g1, w1);
    ISSUE(2, g2, w2);
    ISSUE(3, g3, w3);
    int rounds4 = (rounds + 3) & ~3;
    for (int t0 = 0; t0 < rounds4; t0 += 4) {
      {
        float4 gf = bfq2f4(g0);
        a0.x += w0 * gf.x; a0.y += w0 * gf.y; a0.z += w0 * gf.z; a0.w += w0 * gf.w;
      }
      ISSUE(t0 + 4, g0, w0);
      {
        float4 gf = bfq2f4(g1);
        a1.x += w1 * gf.x; a1.y += w1 * gf.y; a1.z += w1 * gf.z; a1.w += w1 * gf.w;
      }
      ISSUE(t0 + 5, g1, w1);
      {
        float4 gf = bfq2f4(g2);
        a2.x += w2 * gf.x; a2.y += w2 * gf.y; a2.z += w2 * gf.z; a2.w += w2 * gf.w;
      }
      ISSUE(t0 + 6, g2, w2);
      {
        float4 gf = bfq2f4(g3);
        a3.x += w3 * gf.x; a3.y += w3 * gf.y; a3.z += w3 * gf.z; a3.w += w3 * gf.w;
      }
      ISSUE(t0 + 7, g3, w3);
    }
#undef ISSUE
  }

  float sx = (a0.x + a1.x) + (a2.x + a3.x);
  float sy = (a0.y + a1.y) + (a2.y + a3.y);
  float sz = (a0.z + a1.z) + (a2.z + a3.z);
  float sw = (a0.w + a1.w) + (a2.w + a3.w);
  sx += __shfl_down(sx, 32); sy += __shfl_down(sy, 32);
  sz += __shfl_down(sz, 32); sw += __shfl_down(sw, 32);
  sx += __shfl_down(sx, 16); sy += __shfl_down(sy, 16);
  sz += __shfl_down(sz, 16); sw += __shfl_down(sw, 16);
  if (quarter == 0) {
    float4 bv = ((const float4*)bias)[sub];
    float4 o = make_float4(di * sx + bv.x, di * sy + bv.y, di * sz + bv.z, di * sw + bv.w);
    if (relu) {
      o.x = fmaxf(o.x, 0.f);
      o.y = fmaxf(o.y, 0.f);
      o.z = fmaxf(o.z, 0.f);
      o.w = fmaxf(o.w, 0.f);
    }
    if (OUTBF)
      ((uint2*)outv)[(size_t)wid * 16 + sub] = f42bfq(o);
    else
      ((float4*)outv)[(size_t)wid * 16 + sub] = o;
  }
}

// ---------------------------------------------------------------------------
extern "C" void kernel_launch(void* const* d_in, const int* in_sizes, int n_in,
                              void* d_out, int out_size, void* d_ws, size_t ws_size,
                              hipStream_t stream) {
  const float* x = (const float*)d_in[0];
  const int* ei = (const int*)d_in[1];
  const float* W1 = (const float*)d_in[2];
  const float* b1 = (const float*)d_in[3];
  const float* W2 = (const float*)d_in[4];
  const float* b2 = (const float*)d_in[5];

  const int IN = 256;
  const int E = in_sizes[1] / 2;
  const int N = in_sizes[0] / IN;
  const int* src = ei;
  const int* dst = ei + E;
  const int nbins = (N + BIN_NODES - 1) >> BIN_SHIFT;
  const int nsup = (N + (1 << SUP_SHIFT) - 1) >> SUP_SHIFT;

  // workspace carve-up (256B aligned)
  char* ws = (char*)d_ws;
  size_t off = 0;
  auto alloc = [&](size_t bytes) -> void* {
    void* p = ws + off;
    off += (bytes + 255) & ~(size_t)255;
    return p;
  };
  int* count = (int*)alloc((size_t)N * 4);
  int* rowptr = (int*)alloc((size_t)(N + 1) * 4);
  float* dis = (float*)alloc((size_t)N * 4);
  int* binCnt = (int*)alloc(MAX_BINS * 4);
  int* binStart = (int*)alloc((MAX_BINS + 1) * 4);
  int* binCursor = (int*)alloc(MAX_BINS * 4);
  int* supCursor = (int*)alloc(NSUP_MAX * 4);
  int* col = (int*)alloc((size_t)E * 4);                // 12.8 MB; written by bin_csr
  unsigned* supbuf = (unsigned*)col;                    // alias: dead before col written
  uint2* out1 = (uint2*)alloc((size_t)N * 64 * 2);      // bf16 layer-1 activations
  size_t big = ((size_t)E * 4 > (size_t)N * 128) ? (size_t)E * 4 : (size_t)N * 128;
  unsigned* binbuf = (unsigned*)alloc(big);             // aliases h (dead before gemm1)
  uint2* h = (uint2*)binbuf;
  ushort_t* wt1 = (ushort_t*)alloc((size_t)2 * 64 * 256 * 2);  // 64 KB split W1
  ushort_t* wt2 = (ushort_t*)alloc((size_t)2 * 64 * 64 * 2);   // 16 KB split W2
  float* outf = (float*)d_out;

  prep<<<(N + 255) / 256, 256, 0, stream>>>(W1, W2, wt1, wt2, binCnt, nbins, count, N);
  bin_count<<<1024, 256, 0, stream>>>(dst, E, nbins, binCnt);
  bin_scan<<<1, 256, 0, stream>>>(binCnt, nbins, E, binStart, binCursor, supCursor);
  super_fill<<<(E + 2047) / 2048, 256, 0, stream>>>(src, dst, E, nsup, supCursor, supbuf);
  fine_fill<<<nsup * PARTS, 256, 0, stream>>>(supbuf, binStart, nbins, binCursor, binbuf, count, N);
  bin_csr<<<nbins, 256, 0, stream>>>(binbuf, binStart, count, N, E, rowptr, col, dis);

  gemm1_mfma<<<(N + 255) / 256, 256, 0, stream>>>(x, wt1, h, N);
  agg_kernel<true><<<(N + 3) / 4, 256, 0, stream>>>(h, rowptr, col, dis, b1, out1, N, 1);
  gemm2_mfma<<<(N + 127) / 128, 256, 0, stream>>>((const ushort_t*)out1, wt2, h, N);
  agg_kernel<false><<<(N + 3) / 4, 256, 0, stream>>>(h, rowptr, col, dis, b2, outf, N, 0);
}